// Round 11
// baseline (355.196 us; speedup 1.0000x reference)
//
#include <hip/hip_runtime.h>
#include <math.h>

// Problem constants (B=1): S=4096, D=128, NHEADS=4, hd=32, N_COE=50, N_SCALES=4, THRE=5
//
// ws layout (floats):
//   eig   @ 0        (524288)
//   qkv   @ 524288   (1572864; only Q panel used, f32)
//   Oe    @ 2097152  (4*4096*128)
//   E     @ 4194304  (4*4*4096)
//   xsum  @ 4259840  (128)
//   coef  @ 4259968  (104; pad)
//   Khi_g @ 4260352  [h][key][d] bf16 hi
//   Klo_g @ 4522496  [h][key][d] bf16 lo
//   Vt_g  @ 4784640  [h*32+d][key] bf16
//   eT0   @ 5046784  (128)   transposed weights [c][k]
//   eT    @ 5046912  (16384)
//   iT    @ 5063296  (49152)
//   oT    @ 5112448  (16384)
//   w1T   @ 5128832  (16384)
//   w2T   @ 5145216  (16384)

#define KSPLIT 4

typedef __attribute__((ext_vector_type(8))) short short8;   // 8 bf16
typedef __attribute__((ext_vector_type(4))) short short4v;  // 4 bf16 (8B)
typedef __attribute__((ext_vector_type(4))) float f32x4;

__device__ inline unsigned short f2bf(float x) {            // RNE f32->bf16 bits
    unsigned u = __float_as_uint(x);
    return (unsigned short)((u + 0x7FFFu + ((u >> 16) & 1u)) >> 16);
}
__device__ inline float bf2f(unsigned short h) { return __uint_as_float(((unsigned)h) << 16); }

// ---------------- K0: weight transpose to [c][k]; reads coalesced, writes scattered ----------------
__global__ __launch_bounds__(256) void k_wprep(const float* __restrict__ eigW,
    const float* __restrict__ inW, const float* __restrict__ outW,
    const float* __restrict__ W1, const float* __restrict__ W2,
    float* __restrict__ eT0, float* __restrict__ eT, float* __restrict__ iT,
    float* __restrict__ oT, float* __restrict__ w1T, float* __restrict__ w2T)
{
    const int i = blockIdx.x * 256 + threadIdx.x;
    if (i < 16384) {
        const int c = i & 127, j = i >> 7;           // read eigW[(j+1)*128+c]: c fast -> coalesced
        eT[c * 128 + j] = eigW[(j + 1) * 128 + c];
    } else if (i < 65536) {
        const int a = i - 16384;
        const int c = a % 384, k = a / 384;          // read inW[k*384+c]: c fast -> coalesced
        iT[c * 128 + k] = inW[k * 384 + c];
    } else if (i < 81920) {
        const int a = i - 65536; const int c = a & 127, k = a >> 7;
        oT[c * 128 + k] = outW[k * 128 + c];
    } else if (i < 98304) {
        const int a = i - 81920; const int c = a & 127, k = a >> 7;
        w1T[c * 128 + k] = W1[k * 128 + c];
    } else if (i < 114688) {
        const int a = i - 98304; const int c = a & 127, k = a >> 7;
        w2T[c * 128 + k] = W2[k * 128 + c];
    } else if (i < 114816) {
        eT0[i - 114688] = eigW[i - 114688];          // W row 0 (raw-e term)
    }
}

// ---------------- K1: fused sine-encoding + eig GEMM + LN1(shuffle) + qkv GEMM ----------------
// 4 rows/block, 1024 blocks (4 blocks/CU). Thread = (row r = t>>6, lane l = t&63 -> cols l, l+64).
__global__ __launch_bounds__(256) void k_embed(const float* __restrict__ eve,
    const float* __restrict__ eT0, const float* __restrict__ eT, const float* __restrict__ ebias,
    const float* __restrict__ g, const float* __restrict__ b,
    const float* __restrict__ iT, const float* __restrict__ inb,
    float* __restrict__ eig, float* __restrict__ qkv, unsigned short* __restrict__ Khi_g,
    unsigned short* __restrict__ Klo_g, unsigned short* __restrict__ Vt_g)
{
    __shared__ __align__(16) float se[4][132];    // [0..63]=sin, [64..127]=cos, [128]=e
    __shared__ __align__(16) float xn[4][128];    // LN1 output
    __shared__ __align__(16) unsigned short vsh[128][4];
    const int t = threadIdx.x;
    const int r0 = blockIdx.x * 4;
    const int r = t >> 6, l = t & 63;
    {   // Phase A: sin/cos features (one j per lane)
        const float e = eve[r0 + r];
        if (l == 0) se[r][128] = e;
        const float div = __expf(-0.07195578415606394f * (float)(2 * l));
        const float pe = e * 100.0f * div;        // |pe| <= 200 rad
        se[r][l]      = __sinf(pe);
        se[r][64 + l] = __cosf(pe);
    }
    __syncthreads();
    float x0, x1;                                  // eig vals, cols l / l+64 (stay in regs)
    {   // Phase B: eig = eeig @ W + b; col-pair per lane
        const float e = se[r][128];
        float a0 = e * eT0[l];
        float a1 = e * eT0[l + 64];
        #pragma unroll 8
        for (int k = 0; k < 128; k += 4) {
            const float4 xv = *(const float4*)&se[r][k];
            const float4 w0 = *(const float4*)&eT[l * 128 + k];
            const float4 w1 = *(const float4*)&eT[(l + 64) * 128 + k];
            a0 = fmaf(xv.x, w0.x, a0); a0 = fmaf(xv.y, w0.y, a0);
            a0 = fmaf(xv.z, w0.z, a0); a0 = fmaf(xv.w, w0.w, a0);
            a1 = fmaf(xv.x, w1.x, a1); a1 = fmaf(xv.y, w1.y, a1);
            a1 = fmaf(xv.z, w1.z, a1); a1 = fmaf(xv.w, w1.w, a1);
        }
        x0 = a0 + ebias[l];
        x1 = a1 + ebias[l + 64];
        eig[(r0 + r) * 128 + l]      = x0;
        eig[(r0 + r) * 128 + l + 64] = x1;
    }
    {   // Phase C: LN1 via wave shuffle (row = wave; input in regs)
        float s = x0 + x1, ss = x0 * x0 + x1 * x1;
        #pragma unroll
        for (int m = 1; m < 64; m <<= 1) { s += __shfl_xor(s, m); ss += __shfl_xor(ss, m); }
        const float mean = s * (1.f / 128.f);
        const float var  = ss * (1.f / 128.f) - mean * mean;
        const float inv  = 1.f / sqrtf(var + 1e-5f);
        xn[r][l]      = (x0 - mean) * inv * g[l] + b[l];
        xn[r][l + 64] = (x1 - mean) * inv * g[l + 64] + b[l + 64];
    }
    __syncthreads();
    {   // Phase D: qkv GEMM; 6 cols per thread (2 per panel)
        float acc[6];
        acc[0] = inb[l];        acc[1] = inb[l + 64];
        acc[2] = inb[128 + l];  acc[3] = inb[192 + l];
        acc[4] = inb[256 + l];  acc[5] = inb[320 + l];
        #pragma unroll 4
        for (int k = 0; k < 128; k += 4) {
            const float4 xv = *(const float4*)&xn[r][k];
            #pragma unroll
            for (int p = 0; p < 6; ++p) {
                static const int off[6] = {0, 64, 128, 192, 256, 320};
                const float4 w = *(const float4*)&iT[(off[p] + l) * 128 + k];
                float a = acc[p];
                a = fmaf(xv.x, w.x, a); a = fmaf(xv.y, w.y, a);
                a = fmaf(xv.z, w.z, a); a = fmaf(xv.w, w.w, a);
                acc[p] = a;
            }
        }
        const int row = r0 + r;
        qkv[(size_t)row * 384 + l]      = acc[0];
        qkv[(size_t)row * 384 + l + 64] = acc[1];
        {   // K cols l and l+64 of the K panel
            const int h0 = l >> 5, d = l & 31;
            const unsigned short hb0 = f2bf(acc[2]);
            Khi_g[((size_t)h0 * 4096 + row) * 32 + d] = hb0;
            Klo_g[((size_t)h0 * 4096 + row) * 32 + d] = f2bf(acc[2] - bf2f(hb0));
            const int h1 = h0 + 2;
            const unsigned short hb1 = f2bf(acc[3]);
            Khi_g[((size_t)h1 * 4096 + row) * 32 + d] = hb1;
            Klo_g[((size_t)h1 * 4096 + row) * 32 + d] = f2bf(acc[3] - bf2f(hb1));
        }
        vsh[l][r]      = f2bf(acc[4]);
        vsh[l + 64][r] = f2bf(acc[5]);
    }
    __syncthreads();
    if (t < 128) {
        const uint2 vv = *(const uint2*)&vsh[t][0];   // 4 keys of V column t
        *(uint2*)&Vt_g[(size_t)t * 4096 + r0] = vv;
    }
}

// ---------------- K3: MFMA flash attention (no-max linear partials) — unchanged ----------------
#define KSTR 40
#define VSTR 72
#define PSTR 72

__global__ __launch_bounds__(256) void k_attn(const float* __restrict__ qkv,
    const unsigned short* __restrict__ Khi_g, const unsigned short* __restrict__ Klo_g,
    const unsigned short* __restrict__ Vt_g,
    const int* __restrict__ sele, float* __restrict__ Oe, float* __restrict__ E)
{
    __shared__ __align__(16) unsigned short Khi[64 * KSTR];
    __shared__ __align__(16) unsigned short Klo[64 * KSTR];
    __shared__ __align__(16) unsigned short Vt[32 * VSTR];
    __shared__ __align__(16) unsigned short Pb[4][16 * PSTR];

    const int t = threadIdx.x;
    const int lane = t & 63;
    const int l = lane & 15;
    const int quad = lane >> 4;
    const int wv = __builtin_amdgcn_readfirstlane(t >> 6);
    const int qb = blockIdx.x;
    const int h  = blockIdx.y;
    const int ks = blockIdx.z;
    const int nk = sele[0];

    short8 qhi, qlo;
    {
        const float* __restrict__ qr = qkv + (size_t)(qb * 64 + wv * 16 + l) * 384 + h * 32 + quad * 8;
        const float4 a = *(const float4*)qr;
        const float4 b = *(const float4*)(qr + 4);
        const float sc = 0.17677669529663687f;   // 1/sqrt(32)
        float v[8] = {a.x * sc, a.y * sc, a.z * sc, a.w * sc, b.x * sc, b.y * sc, b.z * sc, b.w * sc};
        #pragma unroll
        for (int j = 0; j < 8; ++j) {
            const unsigned short hb = f2bf(v[j]);
            qhi[j] = (short)hb;
            qlo[j] = (short)f2bf(v[j] - bf2f(hb));
        }
    }
    f32x4 accO0 = {0.f, 0.f, 0.f, 0.f};
    f32x4 accO1 = {0.f, 0.f, 0.f, 0.f};
    float elane = 0.f;

    const int kk = t >> 2;
    const int d0 = (t & 3) * 8;
    const int vd = t >> 3;
    const int ko = (t & 7) * 8;

    for (int ch = 0; ch < 16; ++ch) {
        const int keybase = ks * 1024 + ch * 64;
        __syncthreads();
        {
            const uint4 kh16 = *(const uint4*)&Khi_g[((size_t)h * 4096 + keybase + kk) * 32 + d0];
            const uint4 kl16 = *(const uint4*)&Klo_g[((size_t)h * 4096 + keybase + kk) * 32 + d0];
            const uint4 vv16 = *(const uint4*)&Vt_g[((size_t)h * 32 + vd) * 4096 + keybase + ko];
            *(uint4*)&Khi[kk * KSTR + d0] = kh16;
            *(uint4*)&Klo[kk * KSTR + d0] = kl16;
            *(uint4*)&Vt[vd * VSTR + ko]  = vv16;
        }
        __syncthreads();
        unsigned short* __restrict__ Pw = Pb[wv];
        #pragma unroll
        for (int tile = 0; tile < 4; ++tile) {
            const int kl = tile * 16 + l;
            const short8 kh = *(const short8*)&Khi[kl * KSTR + quad * 8];
            const short8 kw = *(const short8*)&Klo[kl * KSTR + quad * 8];
            f32x4 S = {0.f, 0.f, 0.f, 0.f};
            S = __builtin_amdgcn_mfma_f32_16x16x32_bf16(kh, qhi, S, 0, 0, 0);
            S = __builtin_amdgcn_mfma_f32_16x16x32_bf16(kw, qhi, S, 0, 0, 0);
            S = __builtin_amdgcn_mfma_f32_16x16x32_bf16(kh, qlo, S, 0, 0, 0);
            const int kg0 = keybase + tile * 16 + quad * 4;
            short4v pw;
            #pragma unroll
            for (int r = 0; r < 4; ++r) {
                const float p = (kg0 + r < nk) ? __expf(S[r]) : 0.f;
                elane += p;
                pw[r] = (short)f2bf(p);
            }
            *(short4v*)&Pw[l * PSTR + tile * 16 + quad * 4] = pw;
        }
        #pragma unroll
        for (int step = 0; step < 2; ++step) {
            const short8 pa  = *(const short8*)&Pw[l * PSTR + step * 32 + quad * 8];
            const short8 vb0 = *(const short8*)&Vt[l * VSTR + step * 32 + quad * 8];
            const short8 vb1 = *(const short8*)&Vt[(16 + l) * VSTR + step * 32 + quad * 8];
            accO0 = __builtin_amdgcn_mfma_f32_16x16x32_bf16(pa, vb0, accO0, 0, 0, 0);
            accO1 = __builtin_amdgcn_mfma_f32_16x16x32_bf16(pa, vb1, accO1, 0, 0, 0);
        }
    }
    elane += __shfl_xor(elane, 16, 64);
    elane += __shfl_xor(elane, 32, 64);
    const int qrow0 = qb * 64 + wv * 16;
    if (lane < 16)
        E[((size_t)ks * 4 + h) * 4096 + qrow0 + l] = elane;
    #pragma unroll
    for (int r = 0; r < 4; ++r) {
        const size_t row = qrow0 + quad * 4 + r;
        Oe[((size_t)ks * 4096 + row) * 128 + h * 32 + l]      = accO0[r];
        Oe[((size_t)ks * 4096 + row) * 128 + h * 32 + 16 + l] = accO1[r];
    }
}

// ---------------- K4: fold + out-proj + residual + LN2(shuffle) + FFN + column-sum ----------------
// 4 rows/block, 1024 blocks. Thread = (row r = t>>6, lane l = t&63 -> cols l, l+64).
__global__ __launch_bounds__(256) void k_ffn(const float* __restrict__ eig,
    const float* __restrict__ Oe, const float* __restrict__ E,
    const float* __restrict__ oT, const float* __restrict__ outb,
    const float* __restrict__ lg, const float* __restrict__ lb,
    const float* __restrict__ w1T, const float* __restrict__ b1,
    const float* __restrict__ w2T, const float* __restrict__ b2,
    const int* __restrict__ sele, float* __restrict__ xsum)
{
    __shared__ __align__(16) float sA[4][128];    // O rows, later gelu(h)
    __shared__ __align__(16) float xn[4][128];    // LN2 output
    __shared__ float sEr[4][4];
    __shared__ float colsum[4][128];
    const int t = threadIdx.x;
    const int r0 = blockIdx.x * 4;
    const int r = t >> 6, l = t & 63;
    if (l < 4) {
        float es = 0.f;
        #pragma unroll
        for (int ks = 0; ks < KSPLIT; ++ks)
            es += E[((size_t)ks * 4 + l) * 4096 + r0 + r];
        sEr[r][l] = 1.f / es;
    }
    __syncthreads();
    {   // fold 4 slots -> O row (cols l, l+64)
        float v0 = 0.f, v1 = 0.f;
        #pragma unroll
        for (int ks = 0; ks < KSPLIT; ++ks) {
            const float* __restrict__ os = Oe + ((size_t)ks * 4096 + r0 + r) * 128;
            v0 += os[l];
            v1 += os[l + 64];
        }
        sA[r][l]      = v0 * sEr[r][l >> 5];
        sA[r][l + 64] = v1 * sEr[r][(l + 64) >> 5];
    }
    __syncthreads();
    float x20, x21;                                // residual stream (regs only)
    {   // out projection + residual
        float a0 = outb[l], a1 = outb[l + 64];
        #pragma unroll 8
        for (int k = 0; k < 128; k += 4) {
            const float4 xv = *(const float4*)&sA[r][k];
            const float4 w0 = *(const float4*)&oT[l * 128 + k];
            const float4 w1 = *(const float4*)&oT[(l + 64) * 128 + k];
            a0 = fmaf(xv.x, w0.x, a0); a0 = fmaf(xv.y, w0.y, a0);
            a0 = fmaf(xv.z, w0.z, a0); a0 = fmaf(xv.w, w0.w, a0);
            a1 = fmaf(xv.x, w1.x, a1); a1 = fmaf(xv.y, w1.y, a1);
            a1 = fmaf(xv.z, w1.z, a1); a1 = fmaf(xv.w, w1.w, a1);
        }
        x20 = eig[(size_t)(r0 + r) * 128 + l] + a0;
        x21 = eig[(size_t)(r0 + r) * 128 + l + 64] + a1;
    }
    {   // LN2 via wave shuffle
        float s = x20 + x21, ss = x20 * x20 + x21 * x21;
        #pragma unroll
        for (int m = 1; m < 64; m <<= 1) { s += __shfl_xor(s, m); ss += __shfl_xor(ss, m); }
        const float mean = s * (1.f / 128.f);
        const float var  = ss * (1.f / 128.f) - mean * mean;
        const float inv  = 1.f / sqrtf(var + 1e-5f);
        xn[r][l]      = (x20 - mean) * inv * lg[l] + lb[l];
        xn[r][l + 64] = (x21 - mean) * inv * lg[l + 64] + lb[l + 64];
    }
    __syncthreads();
    {   // FFN1 + exact gelu -> sA
        float a0 = b1[l], a1 = b1[l + 64];
        #pragma unroll 8
        for (int k = 0; k < 128; k += 4) {
            const float4 xv = *(const float4*)&xn[r][k];
            const float4 w0 = *(const float4*)&w1T[l * 128 + k];
            const float4 w1 = *(const float4*)&w1T[(l + 64) * 128 + k];
            a0 = fmaf(xv.x, w0.x, a0); a0 = fmaf(xv.y, w0.y, a0);
            a0 = fmaf(xv.z, w0.z, a0); a0 = fmaf(xv.w, w0.w, a0);
            a1 = fmaf(xv.x, w1.x, a1); a1 = fmaf(xv.y, w1.y, a1);
            a1 = fmaf(xv.z, w1.z, a1); a1 = fmaf(xv.w, w1.w, a1);
        }
        __syncthreads();                           // all out-proj reads of sA done
        sA[r][l]      = 0.5f * a0 * (1.f + erff(a0 * 0.70710678118654752f));
        sA[r][l + 64] = 0.5f * a1 * (1.f + erff(a1 * 0.70710678118654752f));
    }
    __syncthreads();
    {   // FFN2 + residual + masked column sum
        float a0 = b2[l], a1 = b2[l + 64];
        #pragma unroll 8
        for (int k = 0; k < 128; k += 4) {
            const float4 xv = *(const float4*)&sA[r][k];
            const float4 w0 = *(const float4*)&w2T[l * 128 + k];
            const float4 w1 = *(const float4*)&w2T[(l + 64) * 128 + k];
            a0 = fmaf(xv.x, w0.x, a0); a0 = fmaf(xv.y, w0.y, a0);
            a0 = fmaf(xv.z, w0.z, a0); a0 = fmaf(xv.w, w0.w, a0);
            a1 = fmaf(xv.x, w1.x, a1); a1 = fmaf(xv.y, w1.y, a1);
            a1 = fmaf(xv.z, w1.z, a1); a1 = fmaf(xv.w, w1.w, a1);
        }
        const bool in = (r0 + r) < sele[0];
        colsum[r][l]      = in ? (x20 + a0) : 0.f;
        colsum[r][l + 64] = in ? (x21 + a1) : 0.f;
    }
    __syncthreads();
    if (t < 128)
        atomicAdd(&xsum[t], (colsum[0][t] + colsum[1][t]) + (colsum[2][t] + colsum[3][t]));
}

// ---------------- K5: pooled coefficients (parallel k-split) ----------------
__global__ __launch_bounds__(512) void k_coef(const float* __restrict__ xsum,
    const float* __restrict__ dscW, const float* __restrict__ dscb,
    const float* __restrict__ dwvW, const float* __restrict__ dwvb,
    const float* __restrict__ dssW, const float* __restrict__ dssb,
    const int* __restrict__ len, const int* __restrict__ sele,
    float* __restrict__ coef)
{
    __shared__ float xs[128];
    __shared__ float part[104][4];
    __shared__ float val[104];
    __shared__ float s2[2];
    const int t = threadIdx.x;
    if (t < 128) xs[t] = xsum[t];
    __syncthreads();
    const float invl = 1.f / ((float)len[0] + 1e-8f);
    const float ns = (float)sele[0];
    const int o = t >> 2, lk = t & 3;
    if (o < 104) {
        const float* Wp; int stride, col;
        if (o < 50)       { Wp = dscW; stride = 50; col = o; }
        else if (o < 100) { Wp = dwvW; stride = 50; col = o - 50; }
        else              { Wp = dssW; stride = 4;  col = o - 100; }
        float a = 0.f;
        #pragma unroll
        for (int kk = 0; kk < 32; ++kk) {
            const int k = lk * 32 + kk;
            a = fmaf(xs[k], Wp[k * stride + col], a);
        }
        part[o][lk] = a;
    }
    __syncthreads();
    if (t < 104) {
        const float bias = (t < 50) ? dscb[t] : ((t < 100) ? dwvb[t - 50] : dssb[t - 100]);
        float a = ((part[t][0] + part[t][1]) + (part[t][2] + part[t][3]) + ns * bias) * invl;
        val[t] = 1.f / (1.f + __expf(-a));
    }
    __syncthreads();
    if (t == 0) { float s = 0.f; for (int i = 0; i < 50; ++i) s += val[i]; s2[0] = s; }
    if (t == 1) { float s = 0.f; for (int i = 0; i < 50; ++i) s += val[50 + i]; s2[1] = s; }
    __syncthreads();
    if (t < 50) {
        coef[t]      = val[t] / (s2[0] + 1e-8f);
        coef[50 + t] = val[50 + t] / (s2[1] + 1e-8f);
    } else if (t >= 100 && t < 104) {
        coef[t] = val[t] * 5.0f;   // THRE
    }
}

// ---------------- K6: Chebyshev bases + combine + normalize ----------------
__global__ __launch_bounds__(128) void k_out(const float* __restrict__ eve,
    const float* __restrict__ coef, float* __restrict__ out)
{
    __shared__ float csc[50], cwv[50], cs[4];
    const int t = threadIdx.x;
    if (t < 50) csc[t] = coef[t];
    else if (t < 100) cwv[t - 50] = coef[t];
    else if (t < 104) cs[t - 100] = coef[t];
    __syncthreads();
    const int s = blockIdx.x * 128 + t;
    const float e = eve[s];
    float vals[5];
    {
        const float y = e - 1.f;
        float te = 1.f, to = y;
        float a = csc[0] * (0.5f * (1.f - to));
        const float y2 = 2.f * y;
        for (int i = 1; i < 50; ++i) {
            te = fmaf(y2, to, -te);
            to = fmaf(y2, te, -to);
            a = fmaf(csc[i], 0.5f * (1.f - to), a);
        }
        vals[0] = a;
    }
    #pragma unroll
    for (int j = 0; j < 4; ++j) {
        float f = e * cs[j];
        if (f > 2.f) f = 0.f;
        const float y = f - 1.f;
        float te = 1.f, to = y;
        float a = cwv[0] * (0.5f * (1.f - te));
        const float y2 = 2.f * y;
        for (int i = 1; i < 50; ++i) {
            te = fmaf(y2, to, -te);
            to = fmaf(y2, te, -to);
            a = fmaf(cwv[i], 0.5f * (1.f - te), a);
        }
        vals[1 + j] = a;
    }
    float n2 = 0.f;
    #pragma unroll
    for (int k = 0; k < 5; ++k) n2 += vals[k] * vals[k];
    const float invn = 1.f / (sqrtf(n2) + 1e-8f);
    #pragma unroll
    for (int k = 0; k < 5; ++k) out[s * 5 + k] = vals[k] * invn;
}

extern "C" void kernel_launch(void* const* d_in, const int* in_sizes, int n_in,
                              void* d_out, int out_size, void* d_ws, size_t ws_size,
                              hipStream_t stream) {
    const float* eve  = (const float*)d_in[0];
    const int*   len  = (const int*)d_in[1];
    const int*   sele = (const int*)d_in[2];
    const float* eigW = (const float*)d_in[3];
    const float* eigB = (const float*)d_in[4];
    const float* mlg  = (const float*)d_in[5];
    const float* mlb  = (const float*)d_in[6];
    const float* inW  = (const float*)d_in[7];
    const float* inb  = (const float*)d_in[8];
    const float* outW = (const float*)d_in[9];
    const float* outb = (const float*)d_in[10];
    const float* flg  = (const float*)d_in[11];
    const float* flb  = (const float*)d_in[12];
    const float* W1   = (const float*)d_in[13];
    const float* b1   = (const float*)d_in[14];
    const float* W2   = (const float*)d_in[15];
    const float* b2   = (const float*)d_in[16];
    const float* dscW = (const float*)d_in[17];
    const float* dscb = (const float*)d_in[18];
    const float* dwvW = (const float*)d_in[19];
    const float* dwvb = (const float*)d_in[20];
    const float* dssW = (const float*)d_in[21];
    const float* dssb = (const float*)d_in[22];

    float* ws   = (float*)d_ws;
    float* eig  = ws;
    float* qkv  = ws + 524288;
    float* Oe   = ws + 2097152;
    float* E    = ws + 4194304;
    float* xsum = ws + 4259840;
    float* coef = ws + 4259968;
    unsigned short* Khi_g = (unsigned short*)(ws + 4260352);
    unsigned short* Klo_g = (unsigned short*)(ws + 4522496);
    unsigned short* Vt_g  = (unsigned short*)(ws + 4784640);
    float* eT0  = ws + 5046784;
    float* eT   = ws + 5046912;
    float* iT   = ws + 5063296;
    float* oT   = ws + 5112448;
    float* w1T  = ws + 5128832;
    float* w2T  = ws + 5145216;
    float* out  = (float*)d_out;

    hipMemsetAsync(xsum, 0, 128 * sizeof(float), stream);
    k_wprep<<<449, 256, 0, stream>>>(eigW, inW, outW, W1, W2, eT0, eT, iT, oT, w1T, w2T);
    k_embed<<<1024, 256, 0, stream>>>(eve, eT0, eT, eigB, mlg, mlb, iT, inb,
                                      eig, qkv, Khi_g, Klo_g, Vt_g);
    k_attn <<<dim3(64, 4, KSPLIT), 256, 0, stream>>>(qkv, Khi_g, Klo_g, Vt_g, sele, Oe, E);
    k_ffn  <<<1024, 256, 0, stream>>>(eig, Oe, E, oT, outb, flg, flb, w1T, b1, w2T, b2, sele, xsum);
    k_coef <<<1, 512, 0, stream>>>(xsum, dscW, dscb, dwvW, dwvb, dssW, dssb, len, sele, coef);
    k_out  <<<32, 128, 0, stream>>>(eve, coef, out);
}

// Round 12
// 213.194 us; speedup vs baseline: 1.6661x; 1.6661x over previous
//
#include <hip/hip_runtime.h>
#include <math.h>

// Problem constants (B=1): S=4096, D=128, NHEADS=4, hd=32, N_COE=50, N_SCALES=4, THRE=5
//
// ws layout (floats):
//   eig   @ 0        (524288)
//   qkv   @ 524288   (1572864; only Q panel used, f32)
//   Oe    @ 2097152  (4*4096*128)
//   E     @ 4194304  (4*4*4096)
//   xsum  @ 4259840  (128)
//   coef  @ 4259968  (104; pad)
//   Khi_g @ 4260352  [h][key][d] bf16 hi
//   Klo_g @ 4522496  [h][key][d] bf16 lo
//   Vt_g  @ 4784640  [h*32+d][key] bf16
// total ~20 MB

#define KSPLIT 4

typedef __attribute__((ext_vector_type(8))) short short8;   // 8 bf16
typedef __attribute__((ext_vector_type(4))) short short4v;  // 4 bf16 (8B)
typedef __attribute__((ext_vector_type(4))) float f32x4;

__device__ inline unsigned short f2bf(float x) {            // RNE f32->bf16 bits
    unsigned u = __float_as_uint(x);
    return (unsigned short)((u + 0x7FFFu + ((u >> 16) & 1u)) >> 16);
}
__device__ inline float bf2f(unsigned short h) { return __uint_as_float(((unsigned)h) << 16); }

// ---------------- K1: fused sine-encoding + eig GEMM + LN1 + qkv GEMM ----------------
// 8 rows/block, 512 blocks. GEMM thread map: wave w (=t>>6) + sub (=lane>>5) -> row w*2+sub;
// lane&31 -> 4-col group. Weight loads: float4 at W[k*128 + 4*(lane&31)] — native [k][c]
// layout, CONTIGUOUS across the half-wave (coalesced) and vectorized.
__global__ __launch_bounds__(256) void k_embed(const float* __restrict__ eve,
    const float* __restrict__ eigW, const float* __restrict__ ebias,
    const float* __restrict__ g, const float* __restrict__ b,
    const float* __restrict__ inW, const float* __restrict__ inb,
    float* __restrict__ eig, float* __restrict__ qkv, unsigned short* __restrict__ Khi_g,
    unsigned short* __restrict__ Klo_g, unsigned short* __restrict__ Vt_g)
{
    __shared__ __align__(16) float se[8][132];    // [0..63]=sin, [64..127]=cos, [128]=e
    __shared__ __align__(16) float xn[8][132];    // LN1 output
    __shared__ __align__(16) unsigned short vsh[128][8];
    const int t = threadIdx.x;
    const int r0 = blockIdx.x * 8;
    {   // Phase A: sin/cos features (8 rows x 32 lanes x 2 j)
        const int r = t >> 5, l = t & 31;
        const float e = eve[r0 + r];
        if (l == 0) se[r][128] = e;
        #pragma unroll
        for (int jj = 0; jj < 2; ++jj) {
            const int j = l * 2 + jj;
            const float div = __expf(-0.07195578415606394f * (float)(2 * j));
            const float pe = e * 100.0f * div;    // |pe| <= 200 rad
            se[r][j]      = __sinf(pe);
            se[r][64 + j] = __cosf(pe);
        }
    }
    __syncthreads();
    const int lane = t & 63;
    const int w = t >> 6;
    const int sub = lane >> 5;
    const int r = w * 2 + sub;                    // this thread's row (0..7)
    const int c0 = (lane & 31) * 4;               // this thread's 4 cols
    const int row = r0 + r;
    float xa[4];                                   // eig row r, cols c0..c0+3 (stay in regs)
    {   // Phase B: eig = eeig @ W + b
        const float e = se[r][128];
        const float4 w0 = *(const float4*)&eigW[c0];           // row 0 pairs raw e
        float a0 = e * w0.x, a1 = e * w0.y, a2 = e * w0.z, a3 = e * w0.w;
        #pragma unroll 8
        for (int k = 0; k < 128; k += 4) {        // se[.][k] pairs eigW[k+1]
            const float4 xv = *(const float4*)&se[r][k];
            const float4 wk0 = *(const float4*)&eigW[(k + 1) * 128 + c0];
            const float4 wk1 = *(const float4*)&eigW[(k + 2) * 128 + c0];
            const float4 wk2 = *(const float4*)&eigW[(k + 3) * 128 + c0];
            const float4 wk3 = *(const float4*)&eigW[(k + 4) * 128 + c0];
            a0 = fmaf(xv.x, wk0.x, a0); a1 = fmaf(xv.x, wk0.y, a1);
            a2 = fmaf(xv.x, wk0.z, a2); a3 = fmaf(xv.x, wk0.w, a3);
            a0 = fmaf(xv.y, wk1.x, a0); a1 = fmaf(xv.y, wk1.y, a1);
            a2 = fmaf(xv.y, wk1.z, a2); a3 = fmaf(xv.y, wk1.w, a3);
            a0 = fmaf(xv.z, wk2.x, a0); a1 = fmaf(xv.z, wk2.y, a1);
            a2 = fmaf(xv.z, wk2.z, a2); a3 = fmaf(xv.z, wk2.w, a3);
            a0 = fmaf(xv.w, wk3.x, a0); a1 = fmaf(xv.w, wk3.y, a1);
            a2 = fmaf(xv.w, wk3.z, a2); a3 = fmaf(xv.w, wk3.w, a3);
        }
        const float4 bb = *(const float4*)&ebias[c0];
        xa[0] = a0 + bb.x; xa[1] = a1 + bb.y; xa[2] = a2 + bb.z; xa[3] = a3 + bb.w;
        *(float4*)&eig[(size_t)row * 128 + c0] = make_float4(xa[0], xa[1], xa[2], xa[3]);
    }
    {   // Phase C: LN1 — half-wave shuffle (row lives in 32 lanes)
        float s = (xa[0] + xa[1]) + (xa[2] + xa[3]);
        float ss = (xa[0] * xa[0] + xa[1] * xa[1]) + (xa[2] * xa[2] + xa[3] * xa[3]);
        #pragma unroll
        for (int m = 1; m < 32; m <<= 1) { s += __shfl_xor(s, m, 32); ss += __shfl_xor(ss, m, 32); }
        const float mean = s * (1.f / 128.f);
        const float var  = ss * (1.f / 128.f) - mean * mean;
        const float inv  = 1.f / sqrtf(var + 1e-5f);
        const float4 gg = *(const float4*)&g[c0];
        const float4 bb = *(const float4*)&b[c0];
        xn[r][c0]     = (xa[0] - mean) * inv * gg.x + bb.x;
        xn[r][c0 + 1] = (xa[1] - mean) * inv * gg.y + bb.y;
        xn[r][c0 + 2] = (xa[2] - mean) * inv * gg.z + bb.z;
        xn[r][c0 + 3] = (xa[3] - mean) * inv * gg.w + bb.w;
    }
    __syncthreads();
    {   // Phase D: qkv GEMM, 3 panels x 4 cols
        float acc[3][4];
        #pragma unroll
        for (int p = 0; p < 3; ++p) {
            const float4 bb = *(const float4*)&inb[p * 128 + c0];
            acc[p][0] = bb.x; acc[p][1] = bb.y; acc[p][2] = bb.z; acc[p][3] = bb.w;
        }
        #pragma unroll 4
        for (int k = 0; k < 128; ++k) {
            const float xv = xn[r][k];            // wave-broadcast LDS read
            #pragma unroll
            for (int p = 0; p < 3; ++p) {
                const float4 wk = *(const float4*)&inW[k * 384 + p * 128 + c0];
                acc[p][0] = fmaf(xv, wk.x, acc[p][0]);
                acc[p][1] = fmaf(xv, wk.y, acc[p][1]);
                acc[p][2] = fmaf(xv, wk.z, acc[p][2]);
                acc[p][3] = fmaf(xv, wk.w, acc[p][3]);
            }
        }
        // Q: f32
        *(float4*)&qkv[(size_t)row * 384 + c0] =
            make_float4(acc[0][0], acc[0][1], acc[0][2], acc[0][3]);
        // K: bf16 hi/lo, [h][key][d] (4 contiguous d within one head)
        {
            const int h = c0 >> 5, d = c0 & 31;
            unsigned short hi4[4], lo4[4];
            #pragma unroll
            for (int i = 0; i < 4; ++i) {
                hi4[i] = f2bf(acc[1][i]);
                lo4[i] = f2bf(acc[1][i] - bf2f(hi4[i]));
            }
            *(uint2*)&Khi_g[((size_t)h * 4096 + row) * 32 + d] = *(uint2*)hi4;
            *(uint2*)&Klo_g[((size_t)h * 4096 + row) * 32 + d] = *(uint2*)lo4;
        }
        // V: bf16 via LDS transpose
        #pragma unroll
        for (int i = 0; i < 4; ++i)
            vsh[c0 + i][r] = f2bf(acc[2][i]);
    }
    __syncthreads();
    if (t < 128) {
        const uint4 vv = *(const uint4*)&vsh[t][0];   // 8 keys of V column t
        *(uint4*)&Vt_g[(size_t)t * 4096 + r0] = vv;
    }
}

// ---------------- K3: MFMA flash attention (no-max linear partials) — unchanged ----------------
#define KSTR 40
#define VSTR 72
#define PSTR 72

__global__ __launch_bounds__(256) void k_attn(const float* __restrict__ qkv,
    const unsigned short* __restrict__ Khi_g, const unsigned short* __restrict__ Klo_g,
    const unsigned short* __restrict__ Vt_g,
    const int* __restrict__ sele, float* __restrict__ Oe, float* __restrict__ E)
{
    __shared__ __align__(16) unsigned short Khi[64 * KSTR];
    __shared__ __align__(16) unsigned short Klo[64 * KSTR];
    __shared__ __align__(16) unsigned short Vt[32 * VSTR];
    __shared__ __align__(16) unsigned short Pb[4][16 * PSTR];

    const int t = threadIdx.x;
    const int lane = t & 63;
    const int l = lane & 15;
    const int quad = lane >> 4;
    const int wv = __builtin_amdgcn_readfirstlane(t >> 6);
    const int qb = blockIdx.x;
    const int h  = blockIdx.y;
    const int ks = blockIdx.z;
    const int nk = sele[0];

    short8 qhi, qlo;
    {
        const float* __restrict__ qr = qkv + (size_t)(qb * 64 + wv * 16 + l) * 384 + h * 32 + quad * 8;
        const float4 a = *(const float4*)qr;
        const float4 b = *(const float4*)(qr + 4);
        const float sc = 0.17677669529663687f;   // 1/sqrt(32)
        float v[8] = {a.x * sc, a.y * sc, a.z * sc, a.w * sc, b.x * sc, b.y * sc, b.z * sc, b.w * sc};
        #pragma unroll
        for (int j = 0; j < 8; ++j) {
            const unsigned short hb = f2bf(v[j]);
            qhi[j] = (short)hb;
            qlo[j] = (short)f2bf(v[j] - bf2f(hb));
        }
    }
    f32x4 accO0 = {0.f, 0.f, 0.f, 0.f};
    f32x4 accO1 = {0.f, 0.f, 0.f, 0.f};
    float elane = 0.f;

    const int kk = t >> 2;
    const int d0 = (t & 3) * 8;
    const int vd = t >> 3;
    const int ko = (t & 7) * 8;

    for (int ch = 0; ch < 16; ++ch) {
        const int keybase = ks * 1024 + ch * 64;
        __syncthreads();
        {
            const uint4 kh16 = *(const uint4*)&Khi_g[((size_t)h * 4096 + keybase + kk) * 32 + d0];
            const uint4 kl16 = *(const uint4*)&Klo_g[((size_t)h * 4096 + keybase + kk) * 32 + d0];
            const uint4 vv16 = *(const uint4*)&Vt_g[((size_t)h * 32 + vd) * 4096 + keybase + ko];
            *(uint4*)&Khi[kk * KSTR + d0] = kh16;
            *(uint4*)&Klo[kk * KSTR + d0] = kl16;
            *(uint4*)&Vt[vd * VSTR + ko]  = vv16;
        }
        __syncthreads();
        unsigned short* __restrict__ Pw = Pb[wv];
        #pragma unroll
        for (int tile = 0; tile < 4; ++tile) {
            const int kl = tile * 16 + l;
            const short8 kh = *(const short8*)&Khi[kl * KSTR + quad * 8];
            const short8 kw = *(const short8*)&Klo[kl * KSTR + quad * 8];
            f32x4 S = {0.f, 0.f, 0.f, 0.f};
            S = __builtin_amdgcn_mfma_f32_16x16x32_bf16(kh, qhi, S, 0, 0, 0);
            S = __builtin_amdgcn_mfma_f32_16x16x32_bf16(kw, qhi, S, 0, 0, 0);
            S = __builtin_amdgcn_mfma_f32_16x16x32_bf16(kh, qlo, S, 0, 0, 0);
            const int kg0 = keybase + tile * 16 + quad * 4;
            short4v pw;
            #pragma unroll
            for (int r = 0; r < 4; ++r) {
                const float p = (kg0 + r < nk) ? __expf(S[r]) : 0.f;
                elane += p;
                pw[r] = (short)f2bf(p);
            }
            *(short4v*)&Pw[l * PSTR + tile * 16 + quad * 4] = pw;
        }
        #pragma unroll
        for (int step = 0; step < 2; ++step) {
            const short8 pa  = *(const short8*)&Pw[l * PSTR + step * 32 + quad * 8];
            const short8 vb0 = *(const short8*)&Vt[l * VSTR + step * 32 + quad * 8];
            const short8 vb1 = *(const short8*)&Vt[(16 + l) * VSTR + step * 32 + quad * 8];
            accO0 = __builtin_amdgcn_mfma_f32_16x16x32_bf16(pa, vb0, accO0, 0, 0, 0);
            accO1 = __builtin_amdgcn_mfma_f32_16x16x32_bf16(pa, vb1, accO1, 0, 0, 0);
        }
    }
    elane += __shfl_xor(elane, 16, 64);
    elane += __shfl_xor(elane, 32, 64);
    const int qrow0 = qb * 64 + wv * 16;
    if (lane < 16)
        E[((size_t)ks * 4 + h) * 4096 + qrow0 + l] = elane;
    #pragma unroll
    for (int r = 0; r < 4; ++r) {
        const size_t row = qrow0 + quad * 4 + r;
        Oe[((size_t)ks * 4096 + row) * 128 + h * 32 + l]      = accO0[r];
        Oe[((size_t)ks * 4096 + row) * 128 + h * 32 + 16 + l] = accO1[r];
    }
}

// ---------------- K4: fold + out-proj + residual + LN2 + FFN + column-sum ----------------
// Same coalesced-vectorized map as k_embed: 8 rows/block, 512 blocks; native [k][c] weights.
__global__ __launch_bounds__(256) void k_ffn(const float* __restrict__ eig,
    const float* __restrict__ Oe, const float* __restrict__ E,
    const float* __restrict__ outW, const float* __restrict__ outb,
    const float* __restrict__ lg, const float* __restrict__ lb,
    const float* __restrict__ W1, const float* __restrict__ b1,
    const float* __restrict__ W2, const float* __restrict__ b2,
    const int* __restrict__ sele, float* __restrict__ xsum)
{
    __shared__ __align__(16) float sA[8][132];    // O rows, later gelu(h)
    __shared__ __align__(16) float xn[8][132];    // LN2 output
    __shared__ __align__(16) float colsum[8][132];
    const int t = threadIdx.x;
    const int r0 = blockIdx.x * 8;
    const int lane = t & 63;
    const int w = t >> 6;
    const int sub = lane >> 5;
    const int r = w * 2 + sub;
    const int c0 = (lane & 31) * 4;
    const int row = r0 + r;
    {   // fold 4 key-slots + divide by E
        const int h = c0 >> 5;
        float es = 0.f;
        float v[4] = {0.f, 0.f, 0.f, 0.f};
        #pragma unroll
        for (int ks = 0; ks < KSPLIT; ++ks) {
            es += E[((size_t)ks * 4 + h) * 4096 + row];
            const float4 ov = *(const float4*)&Oe[((size_t)ks * 4096 + row) * 128 + c0];
            v[0] += ov.x; v[1] += ov.y; v[2] += ov.z; v[3] += ov.w;
        }
        const float rcp = 1.f / es;
        sA[r][c0]     = v[0] * rcp;
        sA[r][c0 + 1] = v[1] * rcp;
        sA[r][c0 + 2] = v[2] * rcp;
        sA[r][c0 + 3] = v[3] * rcp;
    }
    __syncthreads();
    float x2[4];                                   // residual stream (regs)
    {   // out projection + residual
        const float4 bb = *(const float4*)&outb[c0];
        float a0 = bb.x, a1 = bb.y, a2 = bb.z, a3 = bb.w;
        #pragma unroll 8
        for (int k = 0; k < 128; ++k) {
            const float xv = sA[r][k];            // broadcast
            const float4 wk = *(const float4*)&outW[k * 128 + c0];
            a0 = fmaf(xv, wk.x, a0); a1 = fmaf(xv, wk.y, a1);
            a2 = fmaf(xv, wk.z, a2); a3 = fmaf(xv, wk.w, a3);
        }
        const float4 ev = *(const float4*)&eig[(size_t)row * 128 + c0];
        x2[0] = ev.x + a0; x2[1] = ev.y + a1; x2[2] = ev.z + a2; x2[3] = ev.w + a3;
    }
    {   // LN2 — half-wave shuffle
        float s = (x2[0] + x2[1]) + (x2[2] + x2[3]);
        float ss = (x2[0] * x2[0] + x2[1] * x2[1]) + (x2[2] * x2[2] + x2[3] * x2[3]);
        #pragma unroll
        for (int m = 1; m < 32; m <<= 1) { s += __shfl_xor(s, m, 32); ss += __shfl_xor(ss, m, 32); }
        const float mean = s * (1.f / 128.f);
        const float var  = ss * (1.f / 128.f) - mean * mean;
        const float inv  = 1.f / sqrtf(var + 1e-5f);
        const float4 gg = *(const float4*)&lg[c0];
        const float4 bb = *(const float4*)&lb[c0];
        xn[r][c0]     = (x2[0] - mean) * inv * gg.x + bb.x;
        xn[r][c0 + 1] = (x2[1] - mean) * inv * gg.y + bb.y;
        xn[r][c0 + 2] = (x2[2] - mean) * inv * gg.z + bb.z;
        xn[r][c0 + 3] = (x2[3] - mean) * inv * gg.w + bb.w;
    }
    __syncthreads();
    {   // FFN1 + exact gelu -> sA
        const float4 bb = *(const float4*)&b1[c0];
        float a0 = bb.x, a1 = bb.y, a2 = bb.z, a3 = bb.w;
        #pragma unroll 8
        for (int k = 0; k < 128; ++k) {
            const float xv = xn[r][k];
            const float4 wk = *(const float4*)&W1[k * 128 + c0];
            a0 = fmaf(xv, wk.x, a0); a1 = fmaf(xv, wk.y, a1);
            a2 = fmaf(xv, wk.z, a2); a3 = fmaf(xv, wk.w, a3);
        }
        __syncthreads();                           // all out-proj reads of sA done
        sA[r][c0]     = 0.5f * a0 * (1.f + erff(a0 * 0.70710678118654752f));
        sA[r][c0 + 1] = 0.5f * a1 * (1.f + erff(a1 * 0.70710678118654752f));
        sA[r][c0 + 2] = 0.5f * a2 * (1.f + erff(a2 * 0.70710678118654752f));
        sA[r][c0 + 3] = 0.5f * a3 * (1.f + erff(a3 * 0.70710678118654752f));
    }
    __syncthreads();
    {   // FFN2 + residual + masked column partial
        const float4 bb = *(const float4*)&b2[c0];
        float a0 = bb.x, a1 = bb.y, a2 = bb.z, a3 = bb.w;
        #pragma unroll 8
        for (int k = 0; k < 128; ++k) {
            const float xv = sA[r][k];
            const float4 wk = *(const float4*)&W2[k * 128 + c0];
            a0 = fmaf(xv, wk.x, a0); a1 = fmaf(xv, wk.y, a1);
            a2 = fmaf(xv, wk.z, a2); a3 = fmaf(xv, wk.w, a3);
        }
        const bool in = row < sele[0];
        colsum[r][c0]     = in ? (x2[0] + a0) : 0.f;
        colsum[r][c0 + 1] = in ? (x2[1] + a1) : 0.f;
        colsum[r][c0 + 2] = in ? (x2[2] + a2) : 0.f;
        colsum[r][c0 + 3] = in ? (x2[3] + a3) : 0.f;
    }
    __syncthreads();
    if (t < 128) {
        float s = 0.f;
        #pragma unroll
        for (int rr = 0; rr < 8; ++rr) s += colsum[rr][t];
        atomicAdd(&xsum[t], s);
    }
}

// ---------------- K5: pooled coefficients (parallel k-split) ----------------
__global__ __launch_bounds__(512) void k_coef(const float* __restrict__ xsum,
    const float* __restrict__ dscW, const float* __restrict__ dscb,
    const float* __restrict__ dwvW, const float* __restrict__ dwvb,
    const float* __restrict__ dssW, const float* __restrict__ dssb,
    const int* __restrict__ len, const int* __restrict__ sele,
    float* __restrict__ coef)
{
    __shared__ float xs[128];
    __shared__ float part[104][4];
    __shared__ float val[104];
    __shared__ float s2[2];
    const int t = threadIdx.x;
    if (t < 128) xs[t] = xsum[t];
    __syncthreads();
    const float invl = 1.f / ((float)len[0] + 1e-8f);
    const float ns = (float)sele[0];
    const int o = t >> 2, lk = t & 3;
    if (o < 104) {
        const float* Wp; int stride, col;
        if (o < 50)       { Wp = dscW; stride = 50; col = o; }
        else if (o < 100) { Wp = dwvW; stride = 50; col = o - 50; }
        else              { Wp = dssW; stride = 4;  col = o - 100; }
        float a = 0.f;
        #pragma unroll
        for (int kk = 0; kk < 32; ++kk) {
            const int k = lk * 32 + kk;
            a = fmaf(xs[k], Wp[k * stride + col], a);
        }
        part[o][lk] = a;
    }
    __syncthreads();
    if (t < 104) {
        const float bias = (t < 50) ? dscb[t] : ((t < 100) ? dwvb[t - 50] : dssb[t - 100]);
        float a = ((part[t][0] + part[t][1]) + (part[t][2] + part[t][3]) + ns * bias) * invl;
        val[t] = 1.f / (1.f + __expf(-a));
    }
    __syncthreads();
    if (t == 0) { float s = 0.f; for (int i = 0; i < 50; ++i) s += val[i]; s2[0] = s; }
    if (t == 1) { float s = 0.f; for (int i = 0; i < 50; ++i) s += val[50 + i]; s2[1] = s; }
    __syncthreads();
    if (t < 50) {
        coef[t]      = val[t] / (s2[0] + 1e-8f);
        coef[50 + t] = val[50 + t] / (s2[1] + 1e-8f);
    } else if (t >= 100 && t < 104) {
        coef[t] = val[t] * 5.0f;   // THRE
    }
}

// ---------------- K6: Chebyshev bases + combine + normalize ----------------
__global__ __launch_bounds__(128) void k_out(const float* __restrict__ eve,
    const float* __restrict__ coef, float* __restrict__ out)
{
    __shared__ float csc[50], cwv[50], cs[4];
    const int t = threadIdx.x;
    if (t < 50) csc[t] = coef[t];
    else if (t < 100) cwv[t - 50] = coef[t];
    else if (t < 104) cs[t - 100] = coef[t];
    __syncthreads();
    const int s = blockIdx.x * 128 + t;
    const float e = eve[s];
    float vals[5];
    {
        const float y = e - 1.f;
        float te = 1.f, to = y;
        float a = csc[0] * (0.5f * (1.f - to));
        const float y2 = 2.f * y;
        for (int i = 1; i < 50; ++i) {
            te = fmaf(y2, to, -te);
            to = fmaf(y2, te, -to);
            a = fmaf(csc[i], 0.5f * (1.f - to), a);
        }
        vals[0] = a;
    }
    #pragma unroll
    for (int j = 0; j < 4; ++j) {
        float f = e * cs[j];
        if (f > 2.f) f = 0.f;
        const float y = f - 1.f;
        float te = 1.f, to = y;
        float a = cwv[0] * (0.5f * (1.f - te));
        const float y2 = 2.f * y;
        for (int i = 1; i < 50; ++i) {
            te = fmaf(y2, to, -te);
            to = fmaf(y2, te, -to);
            a = fmaf(cwv[i], 0.5f * (1.f - te), a);
        }
        vals[1 + j] = a;
    }
    float n2 = 0.f;
    #pragma unroll
    for (int k = 0; k < 5; ++k) n2 += vals[k] * vals[k];
    const float invn = 1.f / (sqrtf(n2) + 1e-8f);
    #pragma unroll
    for (int k = 0; k < 5; ++k) out[s * 5 + k] = vals[k] * invn;
}

extern "C" void kernel_launch(void* const* d_in, const int* in_sizes, int n_in,
                              void* d_out, int out_size, void* d_ws, size_t ws_size,
                              hipStream_t stream) {
    const float* eve  = (const float*)d_in[0];
    const int*   len  = (const int*)d_in[1];
    const int*   sele = (const int*)d_in[2];
    const float* eigW = (const float*)d_in[3];
    const float* eigB = (const float*)d_in[4];
    const float* mlg  = (const float*)d_in[5];
    const float* mlb  = (const float*)d_in[6];
    const float* inW  = (const float*)d_in[7];
    const float* inb  = (const float*)d_in[8];
    const float* outW = (const float*)d_in[9];
    const float* outb = (const float*)d_in[10];
    const float* flg  = (const float*)d_in[11];
    const float* flb  = (const float*)d_in[12];
    const float* W1   = (const float*)d_in[13];
    const float* b1   = (const float*)d_in[14];
    const float* W2   = (const float*)d_in[15];
    const float* b2   = (const float*)d_in[16];
    const float* dscW = (const float*)d_in[17];
    const float* dscb = (const float*)d_in[18];
    const float* dwvW = (const float*)d_in[19];
    const float* dwvb = (const float*)d_in[20];
    const float* dssW = (const float*)d_in[21];
    const float* dssb = (const float*)d_in[22];

    float* ws   = (float*)d_ws;
    float* eig  = ws;
    float* qkv  = ws + 524288;
    float* Oe   = ws + 2097152;
    float* E    = ws + 4194304;
    float* xsum = ws + 4259840;
    float* coef = ws + 4259968;
    unsigned short* Khi_g = (unsigned short*)(ws + 4260352);
    unsigned short* Klo_g = (unsigned short*)(ws + 4522496);
    unsigned short* Vt_g  = (unsigned short*)(ws + 4784640);
    float* out  = (float*)d_out;

    hipMemsetAsync(xsum, 0, 128 * sizeof(float), stream);
    k_embed<<<512, 256, 0, stream>>>(eve, eigW, eigB, mlg, mlb, inW, inb,
                                     eig, qkv, Khi_g, Klo_g, Vt_g);
    k_attn <<<dim3(64, 4, KSPLIT), 256, 0, stream>>>(qkv, Khi_g, Klo_g, Vt_g, sele, Oe, E);
    k_ffn  <<<512, 256, 0, stream>>>(eig, Oe, E, outW, outb, flg, flb, W1, b1, W2, b2, sele, xsum);
    k_coef <<<1, 512, 0, stream>>>(xsum, dscW, dscb, dwvW, dwvb, dssW, dssb, len, sele, coef);
    k_out  <<<32, 128, 0, stream>>>(eve, coef, out);
}

// Round 13
// 199.042 us; speedup vs baseline: 1.7845x; 1.0711x over previous
//
#include <hip/hip_runtime.h>
#include <math.h>

// Problem constants (B=1): S=4096, D=128, NHEADS=4, hd=32, N_COE=50, N_SCALES=4, THRE=5
//
// ws layout (floats):
//   eig   @ 0        (524288)
//   qkv   @ 524288   (1572864; only Q panel used, f32)
//   Oe    @ 2097152  (4*4096*128)
//   E     @ 4194304  (4*4*4096)
//   xsum  @ 4259840  (128)
//   coef  @ 4259968  (104; pad)
//   Khi_g @ 4260352  [h][key][d] bf16 hi
//   Klo_g @ 4522496  [h][key][d] bf16 lo
//   Vt_g  @ 4784640  [h*32+d][key] bf16
// total ~20 MB

#define KSPLIT 4

typedef __attribute__((ext_vector_type(8))) short short8;   // 8 bf16
typedef __attribute__((ext_vector_type(4))) short short4v;  // 4 bf16 (8B)
typedef __attribute__((ext_vector_type(4))) float f32x4;

__device__ inline unsigned short f2bf(float x) {            // RNE f32->bf16 bits
    unsigned u = __float_as_uint(x);
    return (unsigned short)((u + 0x7FFFu + ((u >> 16) & 1u)) >> 16);
}
__device__ inline float bf2f(unsigned short h) { return __uint_as_float(((unsigned)h) << 16); }

// ---------------- K1: fused sine-encoding + eig GEMM + LN1 + qkv GEMM ----------------
// 16 rows/block, 256 blocks. Thread = 2 rows x 4 cols: lane&31 -> col group c0=(lane&31)*4
// (weight float4 loads coalesced across half-wave), row-pair rp = wave*2 + (lane>>5).
// 2 rows/thread halves the per-wave weight re-fetch (the round-12 L2 bottleneck).
__global__ __launch_bounds__(256) void k_embed(const float* __restrict__ eve,
    const float* __restrict__ eigW, const float* __restrict__ ebias,
    const float* __restrict__ g, const float* __restrict__ b,
    const float* __restrict__ inW, const float* __restrict__ inb,
    float* __restrict__ eig, float* __restrict__ qkv, unsigned short* __restrict__ Khi_g,
    unsigned short* __restrict__ Klo_g, unsigned short* __restrict__ Vt_g)
{
    __shared__ __align__(16) float se[16][132];   // [0..63]=sin, [64..127]=cos, [128]=e
    __shared__ __align__(16) float xn[16][132];   // LN1 output
    __shared__ __align__(16) unsigned short vsh[128][16];
    const int t = threadIdx.x;
    const int r0 = blockIdx.x * 16;
    {   // Phase A: sin/cos (16 rows x 16 threads/row x 4 j)
        const int r = t >> 4, l4 = t & 15;
        const float e = eve[r0 + r];
        if (l4 == 0) se[r][128] = e;
        #pragma unroll
        for (int jj = 0; jj < 4; ++jj) {
            const int j = l4 * 4 + jj;
            const float div = __expf(-0.07195578415606394f * (float)(2 * j));
            const float pe = e * 100.0f * div;    // |pe| <= 200 rad
            se[r][j]      = __sinf(pe);
            se[r][64 + j] = __cosf(pe);
        }
    }
    __syncthreads();
    const int lane = t & 63;
    const int w = t >> 6;
    const int rp = w * 2 + (lane >> 5);           // 0..7
    const int c0 = (lane & 31) * 4;
    const int ra = rp * 2, rb = ra + 1;
    float xa[4], xb[4];                            // eig rows ra/rb, cols c0..c0+3
    {   // Phase B: eig = eeig @ W + b
        const float4 w0 = *(const float4*)&eigW[c0];
        const float ea = se[ra][128], eb = se[rb][128];
        float a0 = ea * w0.x, a1 = ea * w0.y, a2 = ea * w0.z, a3 = ea * w0.w;
        float b0 = eb * w0.x, b1 = eb * w0.y, b2 = eb * w0.z, b3 = eb * w0.w;
        #pragma unroll 8
        for (int k = 0; k < 128; ++k) {           // se[.][k] pairs eigW row k+1
            const float xva = se[ra][k];
            const float xvb = se[rb][k];
            const float4 wk = *(const float4*)&eigW[(k + 1) * 128 + c0];
            a0 = fmaf(xva, wk.x, a0); a1 = fmaf(xva, wk.y, a1);
            a2 = fmaf(xva, wk.z, a2); a3 = fmaf(xva, wk.w, a3);
            b0 = fmaf(xvb, wk.x, b0); b1 = fmaf(xvb, wk.y, b1);
            b2 = fmaf(xvb, wk.z, b2); b3 = fmaf(xvb, wk.w, b3);
        }
        const float4 bb = *(const float4*)&ebias[c0];
        xa[0] = a0 + bb.x; xa[1] = a1 + bb.y; xa[2] = a2 + bb.z; xa[3] = a3 + bb.w;
        xb[0] = b0 + bb.x; xb[1] = b1 + bb.y; xb[2] = b2 + bb.z; xb[3] = b3 + bb.w;
        *(float4*)&eig[(size_t)(r0 + ra) * 128 + c0] = make_float4(xa[0], xa[1], xa[2], xa[3]);
        *(float4*)&eig[(size_t)(r0 + rb) * 128 + c0] = make_float4(xb[0], xb[1], xb[2], xb[3]);
    }
    {   // Phase C: LN1 for both rows — half-wave shuffle
        float sa = (xa[0] + xa[1]) + (xa[2] + xa[3]);
        float qa = (xa[0] * xa[0] + xa[1] * xa[1]) + (xa[2] * xa[2] + xa[3] * xa[3]);
        float sb = (xb[0] + xb[1]) + (xb[2] + xb[3]);
        float qb = (xb[0] * xb[0] + xb[1] * xb[1]) + (xb[2] * xb[2] + xb[3] * xb[3]);
        #pragma unroll
        for (int m = 1; m < 32; m <<= 1) {
            sa += __shfl_xor(sa, m, 32); qa += __shfl_xor(qa, m, 32);
            sb += __shfl_xor(sb, m, 32); qb += __shfl_xor(qb, m, 32);
        }
        const float ma = sa * (1.f / 128.f), mb = sb * (1.f / 128.f);
        const float ia = 1.f / sqrtf(qa * (1.f / 128.f) - ma * ma + 1e-5f);
        const float ib = 1.f / sqrtf(qb * (1.f / 128.f) - mb * mb + 1e-5f);
        const float4 gg = *(const float4*)&g[c0];
        const float4 bb = *(const float4*)&b[c0];
        *(float4*)&xn[ra][c0] = make_float4((xa[0] - ma) * ia * gg.x + bb.x,
                                            (xa[1] - ma) * ia * gg.y + bb.y,
                                            (xa[2] - ma) * ia * gg.z + bb.z,
                                            (xa[3] - ma) * ia * gg.w + bb.w);
        *(float4*)&xn[rb][c0] = make_float4((xb[0] - mb) * ib * gg.x + bb.x,
                                            (xb[1] - mb) * ib * gg.y + bb.y,
                                            (xb[2] - mb) * ib * gg.z + bb.z,
                                            (xb[3] - mb) * ib * gg.w + bb.w);
    }
    __syncthreads();
    {   // Phase D: qkv GEMM, 3 panels x 4 cols x 2 rows
        float A[3][4], B[3][4];
        #pragma unroll
        for (int p = 0; p < 3; ++p) {
            const float4 bb = *(const float4*)&inb[p * 128 + c0];
            A[p][0] = bb.x; A[p][1] = bb.y; A[p][2] = bb.z; A[p][3] = bb.w;
            B[p][0] = bb.x; B[p][1] = bb.y; B[p][2] = bb.z; B[p][3] = bb.w;
        }
        #pragma unroll 4
        for (int k = 0; k < 128; ++k) {
            const float xva = xn[ra][k];
            const float xvb = xn[rb][k];
            #pragma unroll
            for (int p = 0; p < 3; ++p) {
                const float4 wk = *(const float4*)&inW[k * 384 + p * 128 + c0];
                A[p][0] = fmaf(xva, wk.x, A[p][0]); A[p][1] = fmaf(xva, wk.y, A[p][1]);
                A[p][2] = fmaf(xva, wk.z, A[p][2]); A[p][3] = fmaf(xva, wk.w, A[p][3]);
                B[p][0] = fmaf(xvb, wk.x, B[p][0]); B[p][1] = fmaf(xvb, wk.y, B[p][1]);
                B[p][2] = fmaf(xvb, wk.z, B[p][2]); B[p][3] = fmaf(xvb, wk.w, B[p][3]);
            }
        }
        const int rowa = r0 + ra, rowb = r0 + rb;
        *(float4*)&qkv[(size_t)rowa * 384 + c0] = make_float4(A[0][0], A[0][1], A[0][2], A[0][3]);
        *(float4*)&qkv[(size_t)rowb * 384 + c0] = make_float4(B[0][0], B[0][1], B[0][2], B[0][3]);
        {   // K bf16 hi/lo, [h][key][d]
            const int h = c0 >> 5, d = c0 & 31;
            unsigned short h4[4], l4v[4];
            #pragma unroll
            for (int i = 0; i < 4; ++i) { h4[i] = f2bf(A[1][i]); l4v[i] = f2bf(A[1][i] - bf2f(h4[i])); }
            *(uint2*)&Khi_g[((size_t)h * 4096 + rowa) * 32 + d] = *(uint2*)h4;
            *(uint2*)&Klo_g[((size_t)h * 4096 + rowa) * 32 + d] = *(uint2*)l4v;
            #pragma unroll
            for (int i = 0; i < 4; ++i) { h4[i] = f2bf(B[1][i]); l4v[i] = f2bf(B[1][i] - bf2f(h4[i])); }
            *(uint2*)&Khi_g[((size_t)h * 4096 + rowb) * 32 + d] = *(uint2*)h4;
            *(uint2*)&Klo_g[((size_t)h * 4096 + rowb) * 32 + d] = *(uint2*)l4v;
        }
        #pragma unroll
        for (int i = 0; i < 4; ++i) {
            vsh[c0 + i][ra] = f2bf(A[2][i]);
            vsh[c0 + i][rb] = f2bf(B[2][i]);
        }
    }
    __syncthreads();
    if (t < 128) {   // V transpose flush: 16 keys of column t
        const uint4 v0 = *(const uint4*)&vsh[t][0];
        const uint4 v1 = *(const uint4*)&vsh[t][8];
        *(uint4*)&Vt_g[(size_t)t * 4096 + r0]     = v0;
        *(uint4*)&Vt_g[(size_t)t * 4096 + r0 + 8] = v1;
    }
}

// ---------------- K3: MFMA flash attention (no-max linear partials) — unchanged ----------------
#define KSTR 40
#define VSTR 72
#define PSTR 72

__global__ __launch_bounds__(256) void k_attn(const float* __restrict__ qkv,
    const unsigned short* __restrict__ Khi_g, const unsigned short* __restrict__ Klo_g,
    const unsigned short* __restrict__ Vt_g,
    const int* __restrict__ sele, float* __restrict__ Oe, float* __restrict__ E)
{
    __shared__ __align__(16) unsigned short Khi[64 * KSTR];
    __shared__ __align__(16) unsigned short Klo[64 * KSTR];
    __shared__ __align__(16) unsigned short Vt[32 * VSTR];
    __shared__ __align__(16) unsigned short Pb[4][16 * PSTR];

    const int t = threadIdx.x;
    const int lane = t & 63;
    const int l = lane & 15;
    const int quad = lane >> 4;
    const int wv = __builtin_amdgcn_readfirstlane(t >> 6);
    const int qb = blockIdx.x;
    const int h  = blockIdx.y;
    const int ks = blockIdx.z;
    const int nk = sele[0];

    short8 qhi, qlo;
    {
        const float* __restrict__ qr = qkv + (size_t)(qb * 64 + wv * 16 + l) * 384 + h * 32 + quad * 8;
        const float4 a = *(const float4*)qr;
        const float4 b = *(const float4*)(qr + 4);
        const float sc = 0.17677669529663687f;   // 1/sqrt(32)
        float v[8] = {a.x * sc, a.y * sc, a.z * sc, a.w * sc, b.x * sc, b.y * sc, b.z * sc, b.w * sc};
        #pragma unroll
        for (int j = 0; j < 8; ++j) {
            const unsigned short hb = f2bf(v[j]);
            qhi[j] = (short)hb;
            qlo[j] = (short)f2bf(v[j] - bf2f(hb));
        }
    }
    f32x4 accO0 = {0.f, 0.f, 0.f, 0.f};
    f32x4 accO1 = {0.f, 0.f, 0.f, 0.f};
    float elane = 0.f;

    const int kk = t >> 2;
    const int d0 = (t & 3) * 8;
    const int vd = t >> 3;
    const int ko = (t & 7) * 8;

    for (int ch = 0; ch < 16; ++ch) {
        const int keybase = ks * 1024 + ch * 64;
        __syncthreads();
        {
            const uint4 kh16 = *(const uint4*)&Khi_g[((size_t)h * 4096 + keybase + kk) * 32 + d0];
            const uint4 kl16 = *(const uint4*)&Klo_g[((size_t)h * 4096 + keybase + kk) * 32 + d0];
            const uint4 vv16 = *(const uint4*)&Vt_g[((size_t)h * 32 + vd) * 4096 + keybase + ko];
            *(uint4*)&Khi[kk * KSTR + d0] = kh16;
            *(uint4*)&Klo[kk * KSTR + d0] = kl16;
            *(uint4*)&Vt[vd * VSTR + ko]  = vv16;
        }
        __syncthreads();
        unsigned short* __restrict__ Pw = Pb[wv];
        #pragma unroll
        for (int tile = 0; tile < 4; ++tile) {
            const int kl = tile * 16 + l;
            const short8 kh = *(const short8*)&Khi[kl * KSTR + quad * 8];
            const short8 kw = *(const short8*)&Klo[kl * KSTR + quad * 8];
            f32x4 S = {0.f, 0.f, 0.f, 0.f};
            S = __builtin_amdgcn_mfma_f32_16x16x32_bf16(kh, qhi, S, 0, 0, 0);
            S = __builtin_amdgcn_mfma_f32_16x16x32_bf16(kw, qhi, S, 0, 0, 0);
            S = __builtin_amdgcn_mfma_f32_16x16x32_bf16(kh, qlo, S, 0, 0, 0);
            const int kg0 = keybase + tile * 16 + quad * 4;
            short4v pw;
            #pragma unroll
            for (int r = 0; r < 4; ++r) {
                const float p = (kg0 + r < nk) ? __expf(S[r]) : 0.f;
                elane += p;
                pw[r] = (short)f2bf(p);
            }
            *(short4v*)&Pw[l * PSTR + tile * 16 + quad * 4] = pw;
        }
        #pragma unroll
        for (int step = 0; step < 2; ++step) {
            const short8 pa  = *(const short8*)&Pw[l * PSTR + step * 32 + quad * 8];
            const short8 vb0 = *(const short8*)&Vt[l * VSTR + step * 32 + quad * 8];
            const short8 vb1 = *(const short8*)&Vt[(16 + l) * VSTR + step * 32 + quad * 8];
            accO0 = __builtin_amdgcn_mfma_f32_16x16x32_bf16(pa, vb0, accO0, 0, 0, 0);
            accO1 = __builtin_amdgcn_mfma_f32_16x16x32_bf16(pa, vb1, accO1, 0, 0, 0);
        }
    }
    elane += __shfl_xor(elane, 16, 64);
    elane += __shfl_xor(elane, 32, 64);
    const int qrow0 = qb * 64 + wv * 16;
    if (lane < 16)
        E[((size_t)ks * 4 + h) * 4096 + qrow0 + l] = elane;
    #pragma unroll
    for (int r = 0; r < 4; ++r) {
        const size_t row = qrow0 + quad * 4 + r;
        Oe[((size_t)ks * 4096 + row) * 128 + h * 32 + l]      = accO0[r];
        Oe[((size_t)ks * 4096 + row) * 128 + h * 32 + 16 + l] = accO1[r];
    }
}

// ---------------- K4: fold + out-proj + residual + LN2 + FFN + column-sum ----------------
// 16 rows/block, 256 blocks; thread = 2 rows x 4 cols (same map as k_embed).
__global__ __launch_bounds__(256) void k_ffn(const float* __restrict__ eig,
    const float* __restrict__ Oe, const float* __restrict__ E,
    const float* __restrict__ outW, const float* __restrict__ outb,
    const float* __restrict__ lg, const float* __restrict__ lb,
    const float* __restrict__ W1, const float* __restrict__ b1,
    const float* __restrict__ W2, const float* __restrict__ b2,
    const int* __restrict__ sele, float* __restrict__ xsum)
{
    __shared__ __align__(16) float sA[16][132];    // O rows, later gelu(h)
    __shared__ __align__(16) float xn[16][132];    // LN2 output
    __shared__ __align__(16) float cs[16][132];    // per-row masked contributions
    const int t = threadIdx.x;
    const int r0 = blockIdx.x * 16;
    {   // fold 4 key-slots + divide by E: thread = (row r, 8-col group)
        const int r = t >> 4, c8 = (t & 15) * 8;
        const int h = c8 >> 5;                     // 8-col group within one head
        float es = 0.f;
        float v[8] = {0.f, 0.f, 0.f, 0.f, 0.f, 0.f, 0.f, 0.f};
        #pragma unroll
        for (int ks = 0; ks < KSPLIT; ++ks) {
            es += E[((size_t)ks * 4 + h) * 4096 + r0 + r];
            const float4 o1 = *(const float4*)&Oe[((size_t)ks * 4096 + r0 + r) * 128 + c8];
            const float4 o2 = *(const float4*)&Oe[((size_t)ks * 4096 + r0 + r) * 128 + c8 + 4];
            v[0] += o1.x; v[1] += o1.y; v[2] += o1.z; v[3] += o1.w;
            v[4] += o2.x; v[5] += o2.y; v[6] += o2.z; v[7] += o2.w;
        }
        const float rcp = 1.f / es;
        *(float4*)&sA[r][c8]     = make_float4(v[0] * rcp, v[1] * rcp, v[2] * rcp, v[3] * rcp);
        *(float4*)&sA[r][c8 + 4] = make_float4(v[4] * rcp, v[5] * rcp, v[6] * rcp, v[7] * rcp);
    }
    __syncthreads();
    const int lane = t & 63;
    const int w = t >> 6;
    const int rp = w * 2 + (lane >> 5);
    const int c0 = (lane & 31) * 4;
    const int ra = rp * 2, rb = ra + 1;
    float x2a[4], x2b[4];                          // residual stream (regs)
    {   // out projection + residual
        const float4 bb = *(const float4*)&outb[c0];
        float a0 = bb.x, a1 = bb.y, a2 = bb.z, a3 = bb.w;
        float b0 = bb.x, b1 = bb.y, b2 = bb.z, b3 = bb.w;
        #pragma unroll 8
        for (int k = 0; k < 128; ++k) {
            const float xva = sA[ra][k];
            const float xvb = sA[rb][k];
            const float4 wk = *(const float4*)&outW[k * 128 + c0];
            a0 = fmaf(xva, wk.x, a0); a1 = fmaf(xva, wk.y, a1);
            a2 = fmaf(xva, wk.z, a2); a3 = fmaf(xva, wk.w, a3);
            b0 = fmaf(xvb, wk.x, b0); b1 = fmaf(xvb, wk.y, b1);
            b2 = fmaf(xvb, wk.z, b2); b3 = fmaf(xvb, wk.w, b3);
        }
        const float4 ea = *(const float4*)&eig[(size_t)(r0 + ra) * 128 + c0];
        const float4 eb = *(const float4*)&eig[(size_t)(r0 + rb) * 128 + c0];
        x2a[0] = ea.x + a0; x2a[1] = ea.y + a1; x2a[2] = ea.z + a2; x2a[3] = ea.w + a3;
        x2b[0] = eb.x + b0; x2b[1] = eb.y + b1; x2b[2] = eb.z + b2; x2b[3] = eb.w + b3;
    }
    {   // LN2 both rows — half-wave shuffle
        float sa = (x2a[0] + x2a[1]) + (x2a[2] + x2a[3]);
        float qa = (x2a[0] * x2a[0] + x2a[1] * x2a[1]) + (x2a[2] * x2a[2] + x2a[3] * x2a[3]);
        float sb = (x2b[0] + x2b[1]) + (x2b[2] + x2b[3]);
        float qb = (x2b[0] * x2b[0] + x2b[1] * x2b[1]) + (x2b[2] * x2b[2] + x2b[3] * x2b[3]);
        #pragma unroll
        for (int m = 1; m < 32; m <<= 1) {
            sa += __shfl_xor(sa, m, 32); qa += __shfl_xor(qa, m, 32);
            sb += __shfl_xor(sb, m, 32); qb += __shfl_xor(qb, m, 32);
        }
        const float ma = sa * (1.f / 128.f), mb = sb * (1.f / 128.f);
        const float ia = 1.f / sqrtf(qa * (1.f / 128.f) - ma * ma + 1e-5f);
        const float ib = 1.f / sqrtf(qb * (1.f / 128.f) - mb * mb + 1e-5f);
        const float4 gg = *(const float4*)&lg[c0];
        const float4 bb = *(const float4*)&lb[c0];
        *(float4*)&xn[ra][c0] = make_float4((x2a[0] - ma) * ia * gg.x + bb.x,
                                            (x2a[1] - ma) * ia * gg.y + bb.y,
                                            (x2a[2] - ma) * ia * gg.z + bb.z,
                                            (x2a[3] - ma) * ia * gg.w + bb.w);
        *(float4*)&xn[rb][c0] = make_float4((x2b[0] - mb) * ib * gg.x + bb.x,
                                            (x2b[1] - mb) * ib * gg.y + bb.y,
                                            (x2b[2] - mb) * ib * gg.z + bb.z,
                                            (x2b[3] - mb) * ib * gg.w + bb.w);
    }
    __syncthreads();                               // also guarantees all sA reads done
    {   // FFN1 + exact gelu -> sA (reuse)
        const float4 bb = *(const float4*)&b1[c0];
        float a0 = bb.x, a1 = bb.y, a2 = bb.z, a3 = bb.w;
        float b0 = bb.x, b1v = bb.y, b2v = bb.z, b3 = bb.w;
        #pragma unroll 8
        for (int k = 0; k < 128; ++k) {
            const float xva = xn[ra][k];
            const float xvb = xn[rb][k];
            const float4 wk = *(const float4*)&W1[k * 128 + c0];
            a0 = fmaf(xva, wk.x, a0); a1 = fmaf(xva, wk.y, a1);
            a2 = fmaf(xva, wk.z, a2); a3 = fmaf(xva, wk.w, a3);
            b0 = fmaf(xvb, wk.x, b0); b1v = fmaf(xvb, wk.y, b1v);
            b2v = fmaf(xvb, wk.z, b2v); b3 = fmaf(xvb, wk.w, b3);
        }
        *(float4*)&sA[ra][c0] = make_float4(
            0.5f * a0 * (1.f + erff(a0 * 0.70710678118654752f)),
            0.5f * a1 * (1.f + erff(a1 * 0.70710678118654752f)),
            0.5f * a2 * (1.f + erff(a2 * 0.70710678118654752f)),
            0.5f * a3 * (1.f + erff(a3 * 0.70710678118654752f)));
        *(float4*)&sA[rb][c0] = make_float4(
            0.5f * b0 * (1.f + erff(b0 * 0.70710678118654752f)),
            0.5f * b1v * (1.f + erff(b1v * 0.70710678118654752f)),
            0.5f * b2v * (1.f + erff(b2v * 0.70710678118654752f)),
            0.5f * b3 * (1.f + erff(b3 * 0.70710678118654752f)));
    }
    __syncthreads();
    {   // FFN2 + residual + masked per-row contributions
        const float4 bb = *(const float4*)&b2[c0];
        float a0 = bb.x, a1 = bb.y, a2 = bb.z, a3 = bb.w;
        float b0 = bb.x, b1v = bb.y, b2v = bb.z, b3 = bb.w;
        #pragma unroll 8
        for (int k = 0; k < 128; ++k) {
            const float xva = sA[ra][k];
            const float xvb = sA[rb][k];
            const float4 wk = *(const float4*)&W2[k * 128 + c0];
            a0 = fmaf(xva, wk.x, a0); a1 = fmaf(xva, wk.y, a1);
            a2 = fmaf(xva, wk.z, a2); a3 = fmaf(xva, wk.w, a3);
            b0 = fmaf(xvb, wk.x, b0); b1v = fmaf(xvb, wk.y, b1v);
            b2v = fmaf(xvb, wk.z, b2v); b3 = fmaf(xvb, wk.w, b3);
        }
        const int nsel = sele[0];
        const bool ina = (r0 + ra) < nsel, inb2 = (r0 + rb) < nsel;
        *(float4*)&cs[ra][c0] = ina ? make_float4(x2a[0] + a0, x2a[1] + a1, x2a[2] + a2, x2a[3] + a3)
                                    : make_float4(0.f, 0.f, 0.f, 0.f);
        *(float4*)&cs[rb][c0] = inb2 ? make_float4(x2b[0] + b0, x2b[1] + b1v, x2b[2] + b2v, x2b[3] + b3)
                                     : make_float4(0.f, 0.f, 0.f, 0.f);
    }
    __syncthreads();
    if (t < 128) {
        float s = 0.f;
        #pragma unroll
        for (int rr = 0; rr < 16; ++rr) s += cs[rr][t];
        atomicAdd(&xsum[t], s);
    }
}

// ---------------- K5: pooled coefficients (parallel k-split) ----------------
__global__ __launch_bounds__(512) void k_coef(const float* __restrict__ xsum,
    const float* __restrict__ dscW, const float* __restrict__ dscb,
    const float* __restrict__ dwvW, const float* __restrict__ dwvb,
    const float* __restrict__ dssW, const float* __restrict__ dssb,
    const int* __restrict__ len, const int* __restrict__ sele,
    float* __restrict__ coef)
{
    __shared__ float xs[128];
    __shared__ float part[104][4];
    __shared__ float val[104];
    __shared__ float s2[2];
    const int t = threadIdx.x;
    if (t < 128) xs[t] = xsum[t];
    __syncthreads();
    const float invl = 1.f / ((float)len[0] + 1e-8f);
    const float ns = (float)sele[0];
    const int o = t >> 2, lk = t & 3;
    if (o < 104) {
        const float* Wp; int stride, col;
        if (o < 50)       { Wp = dscW; stride = 50; col = o; }
        else if (o < 100) { Wp = dwvW; stride = 50; col = o - 50; }
        else              { Wp = dssW; stride = 4;  col = o - 100; }
        float a = 0.f;
        #pragma unroll
        for (int kk = 0; kk < 32; ++kk) {
            const int k = lk * 32 + kk;
            a = fmaf(xs[k], Wp[k * stride + col], a);
        }
        part[o][lk] = a;
    }
    __syncthreads();
    if (t < 104) {
        const float bias = (t < 50) ? dscb[t] : ((t < 100) ? dwvb[t - 50] : dssb[t - 100]);
        float a = ((part[t][0] + part[t][1]) + (part[t][2] + part[t][3]) + ns * bias) * invl;
        val[t] = 1.f / (1.f + __expf(-a));
    }
    __syncthreads();
    if (t == 0) { float s = 0.f; for (int i = 0; i < 50; ++i) s += val[i]; s2[0] = s; }
    if (t == 1) { float s = 0.f; for (int i = 0; i < 50; ++i) s += val[50 + i]; s2[1] = s; }
    __syncthreads();
    if (t < 50) {
        coef[t]      = val[t] / (s2[0] + 1e-8f);
        coef[50 + t] = val[50 + t] / (s2[1] + 1e-8f);
    } else if (t >= 100 && t < 104) {
        coef[t] = val[t] * 5.0f;   // THRE
    }
}

// ---------------- K6: Chebyshev bases + combine + normalize ----------------
__global__ __launch_bounds__(128) void k_out(const float* __restrict__ eve,
    const float* __restrict__ coef, float* __restrict__ out)
{
    __shared__ float csc[50], cwv[50], cssh[4];
    const int t = threadIdx.x;
    if (t < 50) csc[t] = coef[t];
    else if (t < 100) cwv[t - 50] = coef[t];
    else if (t < 104) cssh[t - 100] = coef[t];
    __syncthreads();
    const int s = blockIdx.x * 128 + t;
    const float e = eve[s];
    float vals[5];
    {
        const float y = e - 1.f;
        float te = 1.f, to = y;
        float a = csc[0] * (0.5f * (1.f - to));
        const float y2 = 2.f * y;
        for (int i = 1; i < 50; ++i) {
            te = fmaf(y2, to, -te);
            to = fmaf(y2, te, -to);
            a = fmaf(csc[i], 0.5f * (1.f - to), a);
        }
        vals[0] = a;
    }
    #pragma unroll
    for (int j = 0; j < 4; ++j) {
        float f = e * cssh[j];
        if (f > 2.f) f = 0.f;
        const float y = f - 1.f;
        float te = 1.f, to = y;
        float a = cwv[0] * (0.5f * (1.f - te));
        const float y2 = 2.f * y;
        for (int i = 1; i < 50; ++i) {
            te = fmaf(y2, to, -te);
            to = fmaf(y2, te, -to);
            a = fmaf(cwv[i], 0.5f * (1.f - te), a);
        }
        vals[1 + j] = a;
    }
    float n2 = 0.f;
    #pragma unroll
    for (int k = 0; k < 5; ++k) n2 += vals[k] * vals[k];
    const float invn = 1.f / (sqrtf(n2) + 1e-8f);
    #pragma unroll
    for (int k = 0; k < 5; ++k) out[s * 5 + k] = vals[k] * invn;
}

extern "C" void kernel_launch(void* const* d_in, const int* in_sizes, int n_in,
                              void* d_out, int out_size, void* d_ws, size_t ws_size,
                              hipStream_t stream) {
    const float* eve  = (const float*)d_in[0];
    const int*   len  = (const int*)d_in[1];
    const int*   sele = (const int*)d_in[2];
    const float* eigW = (const float*)d_in[3];
    const float* eigB = (const float*)d_in[4];
    const float* mlg  = (const float*)d_in[5];
    const float* mlb  = (const float*)d_in[6];
    const float* inW  = (const float*)d_in[7];
    const float* inb  = (const float*)d_in[8];
    const float* outW = (const float*)d_in[9];
    const float* outb = (const float*)d_in[10];
    const float* flg  = (const float*)d_in[11];
    const float* flb  = (const float*)d_in[12];
    const float* W1   = (const float*)d_in[13];
    const float* b1   = (const float*)d_in[14];
    const float* W2   = (const float*)d_in[15];
    const float* b2   = (const float*)d_in[16];
    const float* dscW = (const float*)d_in[17];
    const float* dscb = (const float*)d_in[18];
    const float* dwvW = (const float*)d_in[19];
    const float* dwvb = (const float*)d_in[20];
    const float* dssW = (const float*)d_in[21];
    const float* dssb = (const float*)d_in[22];

    float* ws   = (float*)d_ws;
    float* eig  = ws;
    float* qkv  = ws + 524288;
    float* Oe   = ws + 2097152;
    float* E    = ws + 4194304;
    float* xsum = ws + 4259840;
    float* coef = ws + 4259968;
    unsigned short* Khi_g = (unsigned short*)(ws + 4260352);
    unsigned short* Klo_g = (unsigned short*)(ws + 4522496);
    unsigned short* Vt_g  = (unsigned short*)(ws + 4784640);
    float* out  = (float*)d_out;

    hipMemsetAsync(xsum, 0, 128 * sizeof(float), stream);
    k_embed<<<256, 256, 0, stream>>>(eve, eigW, eigB, mlg, mlb, inW, inb,
                                     eig, qkv, Khi_g, Klo_g, Vt_g);
    k_attn <<<dim3(64, 4, KSPLIT), 256, 0, stream>>>(qkv, Khi_g, Klo_g, Vt_g, sele, Oe, E);
    k_ffn  <<<256, 256, 0, stream>>>(eig, Oe, E, outW, outb, flg, flb, W1, b1, W2, b2, sele, xsum);
    k_coef <<<1, 512, 0, stream>>>(xsum, dscW, dscb, dwvW, dwvb, dssW, dssb, len, sele, coef);
    k_out  <<<32, 128, 0, stream>>>(eve, coef, out);
}

// Round 14
// 187.640 us; speedup vs baseline: 1.8930x; 1.0608x over previous
//
#include <hip/hip_runtime.h>
#include <math.h>

// Problem constants (B=1): S=4096, D=128, NHEADS=4, hd=32, N_COE=50, N_SCALES=4, THRE=5
//
// ws layout (floats):
//   eig   @ 0        (524288)
//   qkv   @ 524288   (1572864; only Q panel used, f32)
//   Oe    @ 2097152  (4*4096*128)
//   E     @ 4194304  (4*4*4096)
//   xsum  @ 4259840  (128)
//   coef  @ 4259968  (104; pad)
//   Khi_g @ 4260352  [h][key][d] bf16 hi
//   Klo_g @ 4522496  [h][key][d] bf16 lo
//   Vt_g  @ 4784640  [h*32+d][key] bf16
// total ~20 MB

#define KSPLIT 4

typedef __attribute__((ext_vector_type(8))) short short8;   // 8 bf16
typedef __attribute__((ext_vector_type(4))) short short4v;  // 4 bf16 (8B)
typedef __attribute__((ext_vector_type(4))) float f32x4;

__device__ inline unsigned short f2bf(float x) {            // RNE f32->bf16 bits
    unsigned u = __float_as_uint(x);
    return (unsigned short)((u + 0x7FFFu + ((u >> 16) & 1u)) >> 16);
}
__device__ inline float bf2f(unsigned short h) { return __uint_as_float(((unsigned)h) << 16); }

// ---------------- K1: fused sine-encoding + eig GEMM + LN1 + qkv GEMM ----------------
// 16 rows/block, 256 blocks; thread = 2 rows x 4 cols. NEW: weight panels staged to LDS
// once per block (cooperative float4 copy), GEMM loops read weights from LDS only —
// removes the ~300-cyc global-load latency that capped r12/r13 at ~40 µs (Little's law).
__global__ __launch_bounds__(256) void k_embed(const float* __restrict__ eve,
    const float* __restrict__ eigW, const float* __restrict__ ebias,
    const float* __restrict__ g, const float* __restrict__ b,
    const float* __restrict__ inW, const float* __restrict__ inb,
    float* __restrict__ eig, float* __restrict__ qkv, unsigned short* __restrict__ Khi_g,
    unsigned short* __restrict__ Klo_g, unsigned short* __restrict__ Vt_g)
{
    __shared__ __align__(16) float wsh[129 * 128];   // staged weight panel (66 KB)
    __shared__ __align__(16) float se[16][132];      // [0..63]=sin, [64..127]=cos, [128]=e
    __shared__ __align__(16) float xn[16][132];      // LN1 output
    __shared__ __align__(16) unsigned short vsh[128][16];
    const int t = threadIdx.x;
    const int r0 = blockIdx.x * 16;
    {   // Phase A: sin/cos (16 rows x 16 threads/row x 4 j)
        const int r = t >> 4, l4 = t & 15;
        const float e = eve[r0 + r];
        if (l4 == 0) se[r][128] = e;
        #pragma unroll
        for (int jj = 0; jj < 4; ++jj) {
            const int j = l4 * 4 + jj;
            const float div = __expf(-0.07195578415606394f * (float)(2 * j));
            const float pe = e * 100.0f * div;    // |pe| <= 200 rad
            se[r][j]      = __sinf(pe);
            se[r][64 + j] = __cosf(pe);
        }
    }
    {   // stage eigW (129 rows x 128) -> wsh
        const float4* __restrict__ src = (const float4*)eigW;
        float4* dst = (float4*)wsh;
        #pragma unroll
        for (int i = 0; i < 17; ++i) {
            const int f = t + i * 256;
            if (f < 4128) dst[f] = src[f];
        }
    }
    __syncthreads();
    const int lane = t & 63;
    const int w = t >> 6;
    const int rp = w * 2 + (lane >> 5);           // 0..7
    const int c0 = (lane & 31) * 4;
    const int ra = rp * 2, rb = ra + 1;
    float xa[4], xb[4];                            // eig rows ra/rb, cols c0..c0+3
    {   // Phase B: eig = eeig @ W + b (weights from LDS)
        const float4 w0 = *(const float4*)&wsh[c0];
        const float ea = se[ra][128], eb = se[rb][128];
        float a0 = ea * w0.x, a1 = ea * w0.y, a2 = ea * w0.z, a3 = ea * w0.w;
        float b0 = eb * w0.x, b1 = eb * w0.y, b2 = eb * w0.z, b3 = eb * w0.w;
        #pragma unroll 8
        for (int k = 0; k < 128; ++k) {           // se[.][k] pairs wsh row k+1
            const float xva = se[ra][k];
            const float xvb = se[rb][k];
            const float4 wk = *(const float4*)&wsh[(k + 1) * 128 + c0];
            a0 = fmaf(xva, wk.x, a0); a1 = fmaf(xva, wk.y, a1);
            a2 = fmaf(xva, wk.z, a2); a3 = fmaf(xva, wk.w, a3);
            b0 = fmaf(xvb, wk.x, b0); b1 = fmaf(xvb, wk.y, b1);
            b2 = fmaf(xvb, wk.z, b2); b3 = fmaf(xvb, wk.w, b3);
        }
        const float4 bb = *(const float4*)&ebias[c0];
        xa[0] = a0 + bb.x; xa[1] = a1 + bb.y; xa[2] = a2 + bb.z; xa[3] = a3 + bb.w;
        xb[0] = b0 + bb.x; xb[1] = b1 + bb.y; xb[2] = b2 + bb.z; xb[3] = b3 + bb.w;
        *(float4*)&eig[(size_t)(r0 + ra) * 128 + c0] = make_float4(xa[0], xa[1], xa[2], xa[3]);
        *(float4*)&eig[(size_t)(r0 + rb) * 128 + c0] = make_float4(xb[0], xb[1], xb[2], xb[3]);
    }
    {   // Phase C: LN1 for both rows — half-wave shuffle
        float sa = (xa[0] + xa[1]) + (xa[2] + xa[3]);
        float qa = (xa[0] * xa[0] + xa[1] * xa[1]) + (xa[2] * xa[2] + xa[3] * xa[3]);
        float sb = (xb[0] + xb[1]) + (xb[2] + xb[3]);
        float qb = (xb[0] * xb[0] + xb[1] * xb[1]) + (xb[2] * xb[2] + xb[3] * xb[3]);
        #pragma unroll
        for (int m = 1; m < 32; m <<= 1) {
            sa += __shfl_xor(sa, m, 32); qa += __shfl_xor(qa, m, 32);
            sb += __shfl_xor(sb, m, 32); qb += __shfl_xor(qb, m, 32);
        }
        const float ma = sa * (1.f / 128.f), mb = sb * (1.f / 128.f);
        const float ia = 1.f / sqrtf(qa * (1.f / 128.f) - ma * ma + 1e-5f);
        const float ib = 1.f / sqrtf(qb * (1.f / 128.f) - mb * mb + 1e-5f);
        const float4 gg = *(const float4*)&g[c0];
        const float4 bb = *(const float4*)&b[c0];
        *(float4*)&xn[ra][c0] = make_float4((xa[0] - ma) * ia * gg.x + bb.x,
                                            (xa[1] - ma) * ia * gg.y + bb.y,
                                            (xa[2] - ma) * ia * gg.z + bb.z,
                                            (xa[3] - ma) * ia * gg.w + bb.w);
        *(float4*)&xn[rb][c0] = make_float4((xb[0] - mb) * ib * gg.x + bb.x,
                                            (xb[1] - mb) * ib * gg.y + bb.y,
                                            (xb[2] - mb) * ib * gg.z + bb.z,
                                            (xb[3] - mb) * ib * gg.w + bb.w);
    }
    // Phase D: qkv GEMM, one panel at a time (stage -> gemm -> writeback)
    const int rowa = r0 + ra, rowb = r0 + rb;
    for (int p = 0; p < 3; ++p) {
        __syncthreads();                           // prev wsh reads done; xn ready (p==0)
        {   // stage inW panel p: wsh[k*128+c] = inW[k*384 + p*128 + c]
            const float4* __restrict__ src = (const float4*)inW;   // row = 96 float4
            float4* dst = (float4*)wsh;
            #pragma unroll
            for (int i = 0; i < 16; ++i) {
                const int f = t + i * 256;         // 0..4095
                const int k = f >> 5, c4 = f & 31;
                dst[f] = src[k * 96 + p * 32 + c4];
            }
        }
        __syncthreads();
        float A[4], B[4];
        {
            const float4 bb = *(const float4*)&inb[p * 128 + c0];
            A[0] = bb.x; A[1] = bb.y; A[2] = bb.z; A[3] = bb.w;
            B[0] = bb.x; B[1] = bb.y; B[2] = bb.z; B[3] = bb.w;
        }
        #pragma unroll 8
        for (int k = 0; k < 128; ++k) {
            const float xva = xn[ra][k];
            const float xvb = xn[rb][k];
            const float4 wk = *(const float4*)&wsh[k * 128 + c0];
            A[0] = fmaf(xva, wk.x, A[0]); A[1] = fmaf(xva, wk.y, A[1]);
            A[2] = fmaf(xva, wk.z, A[2]); A[3] = fmaf(xva, wk.w, A[3]);
            B[0] = fmaf(xvb, wk.x, B[0]); B[1] = fmaf(xvb, wk.y, B[1]);
            B[2] = fmaf(xvb, wk.z, B[2]); B[3] = fmaf(xvb, wk.w, B[3]);
        }
        if (p == 0) {          // Q: f32
            *(float4*)&qkv[(size_t)rowa * 384 + c0] = make_float4(A[0], A[1], A[2], A[3]);
            *(float4*)&qkv[(size_t)rowb * 384 + c0] = make_float4(B[0], B[1], B[2], B[3]);
        } else if (p == 1) {   // K: bf16 hi/lo, [h][key][d]
            const int h = c0 >> 5, d = c0 & 31;
            unsigned short h4[4], l4v[4];
            #pragma unroll
            for (int i = 0; i < 4; ++i) { h4[i] = f2bf(A[i]); l4v[i] = f2bf(A[i] - bf2f(h4[i])); }
            *(uint2*)&Khi_g[((size_t)h * 4096 + rowa) * 32 + d] = *(uint2*)h4;
            *(uint2*)&Klo_g[((size_t)h * 4096 + rowa) * 32 + d] = *(uint2*)l4v;
            #pragma unroll
            for (int i = 0; i < 4; ++i) { h4[i] = f2bf(B[i]); l4v[i] = f2bf(B[i] - bf2f(h4[i])); }
            *(uint2*)&Khi_g[((size_t)h * 4096 + rowb) * 32 + d] = *(uint2*)h4;
            *(uint2*)&Klo_g[((size_t)h * 4096 + rowb) * 32 + d] = *(uint2*)l4v;
        } else {               // V: bf16 via LDS transpose
            #pragma unroll
            for (int i = 0; i < 4; ++i) {
                vsh[c0 + i][ra] = f2bf(A[i]);
                vsh[c0 + i][rb] = f2bf(B[i]);
            }
        }
    }
    __syncthreads();
    if (t < 128) {   // V transpose flush: 16 keys of column t
        const uint4 v0 = *(const uint4*)&vsh[t][0];
        const uint4 v1 = *(const uint4*)&vsh[t][8];
        *(uint4*)&Vt_g[(size_t)t * 4096 + r0]     = v0;
        *(uint4*)&Vt_g[(size_t)t * 4096 + r0 + 8] = v1;
    }
}

// ---------------- K3: MFMA flash attention (no-max linear partials) — unchanged ----------------
#define KSTR 40
#define VSTR 72
#define PSTR 72

__global__ __launch_bounds__(256) void k_attn(const float* __restrict__ qkv,
    const unsigned short* __restrict__ Khi_g, const unsigned short* __restrict__ Klo_g,
    const unsigned short* __restrict__ Vt_g,
    const int* __restrict__ sele, float* __restrict__ Oe, float* __restrict__ E)
{
    __shared__ __align__(16) unsigned short Khi[64 * KSTR];
    __shared__ __align__(16) unsigned short Klo[64 * KSTR];
    __shared__ __align__(16) unsigned short Vt[32 * VSTR];
    __shared__ __align__(16) unsigned short Pb[4][16 * PSTR];

    const int t = threadIdx.x;
    const int lane = t & 63;
    const int l = lane & 15;
    const int quad = lane >> 4;
    const int wv = __builtin_amdgcn_readfirstlane(t >> 6);
    const int qb = blockIdx.x;
    const int h  = blockIdx.y;
    const int ks = blockIdx.z;
    const int nk = sele[0];

    short8 qhi, qlo;
    {
        const float* __restrict__ qr = qkv + (size_t)(qb * 64 + wv * 16 + l) * 384 + h * 32 + quad * 8;
        const float4 a = *(const float4*)qr;
        const float4 b = *(const float4*)(qr + 4);
        const float sc = 0.17677669529663687f;   // 1/sqrt(32)
        float v[8] = {a.x * sc, a.y * sc, a.z * sc, a.w * sc, b.x * sc, b.y * sc, b.z * sc, b.w * sc};
        #pragma unroll
        for (int j = 0; j < 8; ++j) {
            const unsigned short hb = f2bf(v[j]);
            qhi[j] = (short)hb;
            qlo[j] = (short)f2bf(v[j] - bf2f(hb));
        }
    }
    f32x4 accO0 = {0.f, 0.f, 0.f, 0.f};
    f32x4 accO1 = {0.f, 0.f, 0.f, 0.f};
    float elane = 0.f;

    const int kk = t >> 2;
    const int d0 = (t & 3) * 8;
    const int vd = t >> 3;
    const int ko = (t & 7) * 8;

    for (int ch = 0; ch < 16; ++ch) {
        const int keybase = ks * 1024 + ch * 64;
        __syncthreads();
        {
            const uint4 kh16 = *(const uint4*)&Khi_g[((size_t)h * 4096 + keybase + kk) * 32 + d0];
            const uint4 kl16 = *(const uint4*)&Klo_g[((size_t)h * 4096 + keybase + kk) * 32 + d0];
            const uint4 vv16 = *(const uint4*)&Vt_g[((size_t)h * 32 + vd) * 4096 + keybase + ko];
            *(uint4*)&Khi[kk * KSTR + d0] = kh16;
            *(uint4*)&Klo[kk * KSTR + d0] = kl16;
            *(uint4*)&Vt[vd * VSTR + ko]  = vv16;
        }
        __syncthreads();
        unsigned short* __restrict__ Pw = Pb[wv];
        #pragma unroll
        for (int tile = 0; tile < 4; ++tile) {
            const int kl = tile * 16 + l;
            const short8 kh = *(const short8*)&Khi[kl * KSTR + quad * 8];
            const short8 kw = *(const short8*)&Klo[kl * KSTR + quad * 8];
            f32x4 S = {0.f, 0.f, 0.f, 0.f};
            S = __builtin_amdgcn_mfma_f32_16x16x32_bf16(kh, qhi, S, 0, 0, 0);
            S = __builtin_amdgcn_mfma_f32_16x16x32_bf16(kw, qhi, S, 0, 0, 0);
            S = __builtin_amdgcn_mfma_f32_16x16x32_bf16(kh, qlo, S, 0, 0, 0);
            const int kg0 = keybase + tile * 16 + quad * 4;
            short4v pw;
            #pragma unroll
            for (int r = 0; r < 4; ++r) {
                const float p = (kg0 + r < nk) ? __expf(S[r]) : 0.f;
                elane += p;
                pw[r] = (short)f2bf(p);
            }
            *(short4v*)&Pw[l * PSTR + tile * 16 + quad * 4] = pw;
        }
        #pragma unroll
        for (int step = 0; step < 2; ++step) {
            const short8 pa  = *(const short8*)&Pw[l * PSTR + step * 32 + quad * 8];
            const short8 vb0 = *(const short8*)&Vt[l * VSTR + step * 32 + quad * 8];
            const short8 vb1 = *(const short8*)&Vt[(16 + l) * VSTR + step * 32 + quad * 8];
            accO0 = __builtin_amdgcn_mfma_f32_16x16x32_bf16(pa, vb0, accO0, 0, 0, 0);
            accO1 = __builtin_amdgcn_mfma_f32_16x16x32_bf16(pa, vb1, accO1, 0, 0, 0);
        }
    }
    elane += __shfl_xor(elane, 16, 64);
    elane += __shfl_xor(elane, 32, 64);
    const int qrow0 = qb * 64 + wv * 16;
    if (lane < 16)
        E[((size_t)ks * 4 + h) * 4096 + qrow0 + l] = elane;
    #pragma unroll
    for (int r = 0; r < 4; ++r) {
        const size_t row = qrow0 + quad * 4 + r;
        Oe[((size_t)ks * 4096 + row) * 128 + h * 32 + l]      = accO0[r];
        Oe[((size_t)ks * 4096 + row) * 128 + h * 32 + 16 + l] = accO1[r];
    }
}

// ---------------- K4: fold + out-proj + residual + LN2 + FFN + column-sum ----------------
// 16 rows/block, 256 blocks; thread = 2 rows x 4 cols; weights staged to LDS per phase.
__global__ __launch_bounds__(256) void k_ffn(const float* __restrict__ eig,
    const float* __restrict__ Oe, const float* __restrict__ E,
    const float* __restrict__ outW, const float* __restrict__ outb,
    const float* __restrict__ lg, const float* __restrict__ lb,
    const float* __restrict__ W1, const float* __restrict__ b1,
    const float* __restrict__ W2, const float* __restrict__ b2,
    const int* __restrict__ sele, float* __restrict__ xsum)
{
    __shared__ __align__(16) float wsh[128 * 128];  // staged weight panel (64 KB)
    __shared__ __align__(16) float sA[16][132];     // O rows, later gelu(h)
    __shared__ __align__(16) float xn[16][132];     // LN2 output
    __shared__ __align__(16) float cs[16][132];     // per-row masked contributions
    const int t = threadIdx.x;
    const int r0 = blockIdx.x * 16;
    {   // fold 4 key-slots + divide by E: thread = (row r, 8-col group)
        const int r = t >> 4, c8 = (t & 15) * 8;
        const int h = c8 >> 5;
        float es = 0.f;
        float v[8] = {0.f, 0.f, 0.f, 0.f, 0.f, 0.f, 0.f, 0.f};
        #pragma unroll
        for (int ks = 0; ks < KSPLIT; ++ks) {
            es += E[((size_t)ks * 4 + h) * 4096 + r0 + r];
            const float4 o1 = *(const float4*)&Oe[((size_t)ks * 4096 + r0 + r) * 128 + c8];
            const float4 o2 = *(const float4*)&Oe[((size_t)ks * 4096 + r0 + r) * 128 + c8 + 4];
            v[0] += o1.x; v[1] += o1.y; v[2] += o1.z; v[3] += o1.w;
            v[4] += o2.x; v[5] += o2.y; v[6] += o2.z; v[7] += o2.w;
        }
        const float rcp = 1.f / es;
        *(float4*)&sA[r][c8]     = make_float4(v[0] * rcp, v[1] * rcp, v[2] * rcp, v[3] * rcp);
        *(float4*)&sA[r][c8 + 4] = make_float4(v[4] * rcp, v[5] * rcp, v[6] * rcp, v[7] * rcp);
    }
    {   // stage outW -> wsh (same [k][c] layout, straight copy)
        const float4* __restrict__ src = (const float4*)outW;
        float4* dst = (float4*)wsh;
        #pragma unroll
        for (int i = 0; i < 16; ++i) dst[t + i * 256] = src[t + i * 256];
    }
    __syncthreads();
    const int lane = t & 63;
    const int w = t >> 6;
    const int rp = w * 2 + (lane >> 5);
    const int c0 = (lane & 31) * 4;
    const int ra = rp * 2, rb = ra + 1;
    float x2a[4], x2b[4];
    {   // out projection + residual (weights from LDS)
        const float4 bb = *(const float4*)&outb[c0];
        float a0 = bb.x, a1 = bb.y, a2 = bb.z, a3 = bb.w;
        float b0 = bb.x, b1 = bb.y, b2 = bb.z, b3 = bb.w;
        #pragma unroll 8
        for (int k = 0; k < 128; ++k) {
            const float xva = sA[ra][k];
            const float xvb = sA[rb][k];
            const float4 wk = *(const float4*)&wsh[k * 128 + c0];
            a0 = fmaf(xva, wk.x, a0); a1 = fmaf(xva, wk.y, a1);
            a2 = fmaf(xva, wk.z, a2); a3 = fmaf(xva, wk.w, a3);
            b0 = fmaf(xvb, wk.x, b0); b1 = fmaf(xvb, wk.y, b1);
            b2 = fmaf(xvb, wk.z, b2); b3 = fmaf(xvb, wk.w, b3);
        }
        const float4 ea = *(const float4*)&eig[(size_t)(r0 + ra) * 128 + c0];
        const float4 eb = *(const float4*)&eig[(size_t)(r0 + rb) * 128 + c0];
        x2a[0] = ea.x + a0; x2a[1] = ea.y + a1; x2a[2] = ea.z + a2; x2a[3] = ea.w + a3;
        x2b[0] = eb.x + b0; x2b[1] = eb.y + b1; x2b[2] = eb.z + b2; x2b[3] = eb.w + b3;
    }
    {   // LN2 both rows — half-wave shuffle
        float sa = (x2a[0] + x2a[1]) + (x2a[2] + x2a[3]);
        float qa = (x2a[0] * x2a[0] + x2a[1] * x2a[1]) + (x2a[2] * x2a[2] + x2a[3] * x2a[3]);
        float sb = (x2b[0] + x2b[1]) + (x2b[2] + x2b[3]);
        float qb = (x2b[0] * x2b[0] + x2b[1] * x2b[1]) + (x2b[2] * x2b[2] + x2b[3] * x2b[3]);
        #pragma unroll
        for (int m = 1; m < 32; m <<= 1) {
            sa += __shfl_xor(sa, m, 32); qa += __shfl_xor(qa, m, 32);
            sb += __shfl_xor(sb, m, 32); qb += __shfl_xor(qb, m, 32);
        }
        const float ma = sa * (1.f / 128.f), mb = sb * (1.f / 128.f);
        const float ia = 1.f / sqrtf(qa * (1.f / 128.f) - ma * ma + 1e-5f);
        const float ib = 1.f / sqrtf(qb * (1.f / 128.f) - mb * mb + 1e-5f);
        const float4 gg = *(const float4*)&lg[c0];
        const float4 bb = *(const float4*)&lb[c0];
        *(float4*)&xn[ra][c0] = make_float4((x2a[0] - ma) * ia * gg.x + bb.x,
                                            (x2a[1] - ma) * ia * gg.y + bb.y,
                                            (x2a[2] - ma) * ia * gg.z + bb.z,
                                            (x2a[3] - ma) * ia * gg.w + bb.w);
        *(float4*)&xn[rb][c0] = make_float4((x2b[0] - mb) * ib * gg.x + bb.x,
                                            (x2b[1] - mb) * ib * gg.y + bb.y,
                                            (x2b[2] - mb) * ib * gg.z + bb.z,
                                            (x2b[3] - mb) * ib * gg.w + bb.w);
    }
    __syncthreads();                               // gemm1 wsh/sA reads done; xn visible
    {   // stage W1 -> wsh
        const float4* __restrict__ src = (const float4*)W1;
        float4* dst = (float4*)wsh;
        #pragma unroll
        for (int i = 0; i < 16; ++i) dst[t + i * 256] = src[t + i * 256];
    }
    __syncthreads();
    {   // FFN1 + exact gelu -> sA
        const float4 bb = *(const float4*)&b1[c0];
        float a0 = bb.x, a1 = bb.y, a2 = bb.z, a3 = bb.w;
        float b0 = bb.x, b1v = bb.y, b2v = bb.z, b3 = bb.w;
        #pragma unroll 8
        for (int k = 0; k < 128; ++k) {
            const float xva = xn[ra][k];
            const float xvb = xn[rb][k];
            const float4 wk = *(const float4*)&wsh[k * 128 + c0];
            a0 = fmaf(xva, wk.x, a0); a1 = fmaf(xva, wk.y, a1);
            a2 = fmaf(xva, wk.z, a2); a3 = fmaf(xva, wk.w, a3);
            b0 = fmaf(xvb, wk.x, b0); b1v = fmaf(xvb, wk.y, b1v);
            b2v = fmaf(xvb, wk.z, b2v); b3 = fmaf(xvb, wk.w, b3);
        }
        *(float4*)&sA[ra][c0] = make_float4(
            0.5f * a0 * (1.f + erff(a0 * 0.70710678118654752f)),
            0.5f * a1 * (1.f + erff(a1 * 0.70710678118654752f)),
            0.5f * a2 * (1.f + erff(a2 * 0.70710678118654752f)),
            0.5f * a3 * (1.f + erff(a3 * 0.70710678118654752f)));
        *(float4*)&sA[rb][c0] = make_float4(
            0.5f * b0 * (1.f + erff(b0 * 0.70710678118654752f)),
            0.5f * b1v * (1.f + erff(b1v * 0.70710678118654752f)),
            0.5f * b2v * (1.f + erff(b2v * 0.70710678118654752f)),
            0.5f * b3 * (1.f + erff(b3 * 0.70710678118654752f)));
    }
    __syncthreads();                               // gelu visible; gemm2 wsh reads done
    {   // stage W2 -> wsh
        const float4* __restrict__ src = (const float4*)W2;
        float4* dst = (float4*)wsh;
        #pragma unroll
        for (int i = 0; i < 16; ++i) dst[t + i * 256] = src[t + i * 256];
    }
    __syncthreads();
    {   // FFN2 + residual + masked per-row contributions
        const float4 bb = *(const float4*)&b2[c0];
        float a0 = bb.x, a1 = bb.y, a2 = bb.z, a3 = bb.w;
        float b0 = bb.x, b1v = bb.y, b2v = bb.z, b3 = bb.w;
        #pragma unroll 8
        for (int k = 0; k < 128; ++k) {
            const float xva = sA[ra][k];
            const float xvb = sA[rb][k];
            const float4 wk = *(const float4*)&wsh[k * 128 + c0];
            a0 = fmaf(xva, wk.x, a0); a1 = fmaf(xva, wk.y, a1);
            a2 = fmaf(xva, wk.z, a2); a3 = fmaf(xva, wk.w, a3);
            b0 = fmaf(xvb, wk.x, b0); b1v = fmaf(xvb, wk.y, b1v);
            b2v = fmaf(xvb, wk.z, b2v); b3 = fmaf(xvb, wk.w, b3);
        }
        const int nsel = sele[0];
        const bool ina = (r0 + ra) < nsel, inb2 = (r0 + rb) < nsel;
        *(float4*)&cs[ra][c0] = ina ? make_float4(x2a[0] + a0, x2a[1] + a1, x2a[2] + a2, x2a[3] + a3)
                                    : make_float4(0.f, 0.f, 0.f, 0.f);
        *(float4*)&cs[rb][c0] = inb2 ? make_float4(x2b[0] + b0, x2b[1] + b1v, x2b[2] + b2v, x2b[3] + b3)
                                     : make_float4(0.f, 0.f, 0.f, 0.f);
    }
    __syncthreads();
    if (t < 128) {
        float s = 0.f;
        #pragma unroll
        for (int rr = 0; rr < 16; ++rr) s += cs[rr][t];
        atomicAdd(&xsum[t], s);
    }
}

// ---------------- K5: pooled coefficients (parallel k-split) ----------------
__global__ __launch_bounds__(512) void k_coef(const float* __restrict__ xsum,
    const float* __restrict__ dscW, const float* __restrict__ dscb,
    const float* __restrict__ dwvW, const float* __restrict__ dwvb,
    const float* __restrict__ dssW, const float* __restrict__ dssb,
    const int* __restrict__ len, const int* __restrict__ sele,
    float* __restrict__ coef)
{
    __shared__ float xs[128];
    __shared__ float part[104][4];
    __shared__ float val[104];
    __shared__ float s2[2];
    const int t = threadIdx.x;
    if (t < 128) xs[t] = xsum[t];
    __syncthreads();
    const float invl = 1.f / ((float)len[0] + 1e-8f);
    const float ns = (float)sele[0];
    const int o = t >> 2, lk = t & 3;
    if (o < 104) {
        const float* Wp; int stride, col;
        if (o < 50)       { Wp = dscW; stride = 50; col = o; }
        else if (o < 100) { Wp = dwvW; stride = 50; col = o - 50; }
        else              { Wp = dssW; stride = 4;  col = o - 100; }
        float a = 0.f;
        #pragma unroll
        for (int kk = 0; kk < 32; ++kk) {
            const int k = lk * 32 + kk;
            a = fmaf(xs[k], Wp[k * stride + col], a);
        }
        part[o][lk] = a;
    }
    __syncthreads();
    if (t < 104) {
        const float bias = (t < 50) ? dscb[t] : ((t < 100) ? dwvb[t - 50] : dssb[t - 100]);
        float a = ((part[t][0] + part[t][1]) + (part[t][2] + part[t][3]) + ns * bias) * invl;
        val[t] = 1.f / (1.f + __expf(-a));
    }
    __syncthreads();
    if (t == 0) { float s = 0.f; for (int i = 0; i < 50; ++i) s += val[i]; s2[0] = s; }
    if (t == 1) { float s = 0.f; for (int i = 0; i < 50; ++i) s += val[50 + i]; s2[1] = s; }
    __syncthreads();
    if (t < 50) {
        coef[t]      = val[t] / (s2[0] + 1e-8f);
        coef[50 + t] = val[50 + t] / (s2[1] + 1e-8f);
    } else if (t >= 100 && t < 104) {
        coef[t] = val[t] * 5.0f;   // THRE
    }
}

// ---------------- K6: Chebyshev bases + combine + normalize ----------------
__global__ __launch_bounds__(128) void k_out(const float* __restrict__ eve,
    const float* __restrict__ coef, float* __restrict__ out)
{
    __shared__ float csc[50], cwv[50], cssh[4];
    const int t = threadIdx.x;
    if (t < 50) csc[t] = coef[t];
    else if (t < 100) cwv[t - 50] = coef[t];
    else if (t < 104) cssh[t - 100] = coef[t];
    __syncthreads();
    const int s = blockIdx.x * 128 + t;
    const float e = eve[s];
    float vals[5];
    {
        const float y = e - 1.f;
        float te = 1.f, to = y;
        float a = csc[0] * (0.5f * (1.f - to));
        const float y2 = 2.f * y;
        for (int i = 1; i < 50; ++i) {
            te = fmaf(y2, to, -te);
            to = fmaf(y2, te, -to);
            a = fmaf(csc[i], 0.5f * (1.f - to), a);
        }
        vals[0] = a;
    }
    #pragma unroll
    for (int j = 0; j < 4; ++j) {
        float f = e * cssh[j];
        if (f > 2.f) f = 0.f;
        const float y = f - 1.f;
        float te = 1.f, to = y;
        float a = cwv[0] * (0.5f * (1.f - te));
        const float y2 = 2.f * y;
        for (int i = 1; i < 50; ++i) {
            te = fmaf(y2, to, -te);
            to = fmaf(y2, te, -to);
            a = fmaf(cwv[i], 0.5f * (1.f - te), a);
        }
        vals[1 + j] = a;
    }
    float n2 = 0.f;
    #pragma unroll
    for (int k = 0; k < 5; ++k) n2 += vals[k] * vals[k];
    const float invn = 1.f / (sqrtf(n2) + 1e-8f);
    #pragma unroll
    for (int k = 0; k < 5; ++k) out[s * 5 + k] = vals[k] * invn;
}

extern "C" void kernel_launch(void* const* d_in, const int* in_sizes, int n_in,
                              void* d_out, int out_size, void* d_ws, size_t ws_size,
                              hipStream_t stream) {
    const float* eve  = (const float*)d_in[0];
    const int*   len  = (const int*)d_in[1];
    const int*   sele = (const int*)d_in[2];
    const float* eigW = (const float*)d_in[3];
    const float* eigB = (const float*)d_in[4];
    const float* mlg  = (const float*)d_in[5];
    const float* mlb  = (const float*)d_in[6];
    const float* inW  = (const float*)d_in[7];
    const float* inb  = (const float*)d_in[8];
    const float* outW = (const float*)d_in[9];
    const float* outb = (const float*)d_in[10];
    const float* flg  = (const float*)d_in[11];
    const float* flb  = (const float*)d_in[12];
    const float* W1   = (const float*)d_in[13];
    const float* b1   = (const float*)d_in[14];
    const float* W2   = (const float*)d_in[15];
    const float* b2   = (const float*)d_in[16];
    const float* dscW = (const float*)d_in[17];
    const float* dscb = (const float*)d_in[18];
    const float* dwvW = (const float*)d_in[19];
    const float* dwvb = (const float*)d_in[20];
    const float* dssW = (const float*)d_in[21];
    const float* dssb = (const float*)d_in[22];

    float* ws   = (float*)d_ws;
    float* eig  = ws;
    float* qkv  = ws + 524288;
    float* Oe   = ws + 2097152;
    float* E    = ws + 4194304;
    float* xsum = ws + 4259840;
    float* coef = ws + 4259968;
    unsigned short* Khi_g = (unsigned short*)(ws + 4260352);
    unsigned short* Klo_g = (unsigned short*)(ws + 4522496);
    unsigned short* Vt_g  = (unsigned short*)(ws + 4784640);
    float* out  = (float*)d_out;

    hipMemsetAsync(xsum, 0, 128 * sizeof(float), stream);
    k_embed<<<256, 256, 0, stream>>>(eve, eigW, eigB, mlg, mlb, inW, inb,
                                     eig, qkv, Khi_g, Klo_g, Vt_g);
    k_attn <<<dim3(64, 4, KSPLIT), 256, 0, stream>>>(qkv, Khi_g, Klo_g, Vt_g, sele, Oe, E);
    k_ffn  <<<256, 256, 0, stream>>>(eig, Oe, E, outW, outb, flg, flb, W1, b1, W2, b2, sele, xsum);
    k_coef <<<1, 512, 0, stream>>>(xsum, dscW, dscb, dwvW, dwvb, dssW, dssb, len, sele, coef);
    k_out  <<<32, 128, 0, stream>>>(eve, coef, out);
}